// Round 19
// baseline (233.408 us; speedup 1.0000x reference)
//
#include <hip/hip_runtime.h>
#include <hip/hip_bf16.h>
#include <hip/hip_fp8.h>
#include <cmath>

// ---------------------------------------------------------------------------
// GAT 2-layer forward. R19: gather1 fp8 decode via native packed
// v_cvt_pk_f32_fp8 (2 fp8 -> float2 / instruction). Everything else
// identical to R18.
// ---------------------------------------------------------------------------

#define HEADS1 8
#define F1 256
#define F2 64
#define NEG_SLOPE 0.2f

typedef unsigned int uint;
typedef unsigned short ushort_t;
typedef unsigned char uchar_t;
typedef __attribute__((ext_vector_type(8))) short bf16x8;
typedef __attribute__((ext_vector_type(4))) float f32x4;
typedef __attribute__((ext_vector_type(2))) float f32x2;

__device__ __forceinline__ float lrelu(float x) {
  return x >= 0.f ? x : NEG_SLOPE * x;
}
__device__ __forceinline__ ushort_t f2bf(float f) {
  uint u = __float_as_uint(f);
  return (ushort_t)((u + 0x7FFFu + ((u >> 16) & 1u)) >> 16);
}
__device__ __forceinline__ float bf2f(ushort_t u) {
  return __uint_as_float(((uint)u) << 16);
}
__device__ __forceinline__ uint pack2(float a, float b) {
  return (uint)f2bf(a) | ((uint)f2bf(b) << 16);
}
__device__ __forceinline__ uchar_t f2fp8(float f) {
  __hip_fp8_e4m3 t(f);
  return (uchar_t)t.__x;
}
__device__ __forceinline__ float fp82f(uchar_t u) {
  __hip_fp8_e4m3 t;
  t.__x = (__hip_fp8_storage_t)u;
  return (float)t;
}

// decode 4 packed fp8 (one dword) -> f32x4
__device__ __forceinline__ f32x4 fp8x4_decode(uint hv) {
#if __has_builtin(__builtin_amdgcn_cvt_pk_f32_fp8)
  f32x2 lo = __builtin_amdgcn_cvt_pk_f32_fp8((int)hv, false);
  f32x2 hi = __builtin_amdgcn_cvt_pk_f32_fp8((int)hv, true);
  return (f32x4){lo.x, lo.y, hi.x, hi.y};
#else
  return (f32x4){fp82f((uchar_t)(hv & 0xff)),
                 fp82f((uchar_t)((hv >> 8) & 0xff)),
                 fp82f((uchar_t)((hv >> 16) & 0xff)),
                 fp82f((uchar_t)(hv >> 24))};
#endif
}

// --------------- kernel A: weight prep (197 blocks) + deg_count -------------
__global__ __launch_bounds__(256) void kernelA(
    const float* __restrict__ W1, const float* __restrict__ W2,
    const float* __restrict__ att_src1, const float* __restrict__ att_dst1,
    const float* __restrict__ att_src2, const float* __restrict__ att_dst2,
    ushort_t* __restrict__ W1t, ushort_t* __restrict__ W2t,
    float* __restrict__ Wsrc1, float* __restrict__ Wdst1,
    float* __restrict__ w_s2, float* __restrict__ w_d2,
    const int* __restrict__ ei, int E0, int Etot, int* __restrict__ counts) {
  const int bid = blockIdx.x;
  const int tid = threadIdx.x;
  if (bid < 128) {
    int idx = bid * 256 + tid;
    int r = idx >> 8, c = idx & 255;
    W1t[(size_t)c * 128 + r] = f2bf(W1[idx]);
  } else if (bid < 192) {
    int idx = (bid - 128) * 256 + tid;
    int r = idx >> 6, c = idx & 63;
    W2t[(size_t)c * 256 + r] = f2bf(W2[idx]);
  } else if (bid < 196) {
    int idx = (bid - 192) * 256 + tid;
    int k = idx >> 3, h = idx & 7;
    float as = 0.f, ad = 0.f;
    #pragma unroll
    for (int c = 0; c < 32; ++c) {
      float wv = W1[(size_t)k * 256 + h * 32 + c];
      as += wv * att_src1[h * 32 + c];
      ad += wv * att_dst1[h * 32 + c];
    }
    Wsrc1[idx] = as;
    Wdst1[idx] = ad;
  } else if (bid < 197) {
    int k = tid;
    float as = 0.f, ad = 0.f;
    #pragma unroll
    for (int c = 0; c < 64; ++c) {
      float wv = W2[(size_t)k * 64 + c];
      as += wv * att_src2[c];
      ad += wv * att_dst2[c];
    }
    w_s2[k] = as;
    w_d2[k] = ad;
  } else {
    int e = (bid - 197) * 256 + tid;
    if (e >= Etot) return;
    int d = (e < E0) ? ei[E0 + e] : (e - E0);
    atomicAdd(&counts[d], 1);
  }
}

// ------------- fused exclusive scan: decoupled lookback, 1 kernel -----------
__global__ __launch_bounds__(256) void scan_fused(
    const int* __restrict__ counts, int* __restrict__ row_start,
    int* __restrict__ btot, int n) {
  __shared__ int wsum[4];
  __shared__ int s_prev;
  const int tid = threadIdx.x;
  const int lane = tid & 63;
  const int wid = tid >> 6;
  const int base = blockIdx.x * 1024 + tid * 4;
  int c[4], inc[4];
  #pragma unroll
  for (int j = 0; j < 4; ++j)
    c[j] = (base + j < n) ? counts[base + j] : 0;
  inc[0] = c[0];
  #pragma unroll
  for (int j = 1; j < 4; ++j) inc[j] = inc[j - 1] + c[j];
  int tsum = inc[3];
  int wincl = tsum;
  #pragma unroll
  for (int off = 1; off < 64; off <<= 1) {
    int v = __shfl_up(wincl, off, 64);
    if (lane >= off) wincl += v;
  }
  if (lane == 63) wsum[wid] = wincl;
  __syncthreads();
  int woff = 0;
  #pragma unroll
  for (int j = 0; j < 4; ++j)
    if (j < wid) woff += wsum[j];

  if (tid == 255) atomicExch(&btot[blockIdx.x], woff + wincl);

  if (wid == 0) {
    int run = 0;
    if (lane < blockIdx.x) {
      int v;
      do {
        v = atomicAdd(&btot[lane], 0);
      } while (v == 0);
      run = v;
    }
    #pragma unroll
    for (int off = 32; off > 0; off >>= 1) run += __shfl_xor(run, off, 64);
    if (lane == 0) s_prev = run;
  }
  __syncthreads();

  int prefix = s_prev + woff + (wincl - tsum);
  #pragma unroll
  for (int j = 0; j < 4; ++j)
    if (base + j < n) row_start[base + j + 1] = prefix + inc[j];
  if (blockIdx.x == 0 && tid == 0) row_start[0] = 0;
}

// -------- kernel B: gemm1 + fill_csr + attproj1 (block-range dispatch) ------
__global__ __launch_bounds__(256) void kernelB(
    const float* __restrict__ x, const ushort_t* __restrict__ W1t,
    uchar_t* __restrict__ h1, int M,
    const int* __restrict__ ei, int E0, int Etot,
    const int* __restrict__ row_start, int* __restrict__ cursor,
    int* __restrict__ csr_src,
    const float* __restrict__ Wsrc, const float* __restrict__ Wdst,
    float* __restrict__ a_src, float* __restrict__ a_dst,
    int GB1, int FB) {
  __shared__ char smem[10240];
  const int bid = blockIdx.x;
  const int tid = threadIdx.x;

  if (bid < GB1) {
    ushort_t* As = (ushort_t*)smem;
    ushort_t* Bs = As + 64 * 40;
    const int lane = tid & 63;
    const int wave = tid >> 6;
    const int wr = wave >> 1, wc = wave & 1;
    const int row0 = (bid >> 2) * 64, col0 = (bid & 3) * 64;
    const int sr = tid >> 2;
    const int sk = (tid & 3) * 8;
    const int l15 = lane & 15;
    const int lk8 = (lane >> 4) * 8;
    const int K = 128;

    f32x4 acc[2][2];
    #pragma unroll
    for (int i = 0; i < 2; ++i)
      #pragma unroll
      for (int j = 0; j < 2; ++j) acc[i][j] = (f32x4){0.f, 0.f, 0.f, 0.f};

    for (int k0 = 0; k0 < K; k0 += 32) {
      const int gr = row0 + sr;
      float4 f0 = {0.f, 0.f, 0.f, 0.f}, f1 = {0.f, 0.f, 0.f, 0.f};
      if (gr < M) {
        f0 = *(const float4*)&x[(size_t)gr * K + k0 + sk];
        f1 = *(const float4*)&x[(size_t)gr * K + k0 + sk + 4];
      }
      uint4 av;
      av.x = pack2(f0.x, f0.y);
      av.y = pack2(f0.z, f0.w);
      av.z = pack2(f1.x, f1.y);
      av.w = pack2(f1.z, f1.w);
      *(uint4*)&As[sr * 40 + sk] = av;
      uint4 bv = *(const uint4*)&W1t[(size_t)(col0 + sr) * K + k0 + sk];
      *(uint4*)&Bs[sr * 40 + sk] = bv;
      __syncthreads();

      bf16x8 af[2], bfr[2];
      #pragma unroll
      for (int mi = 0; mi < 2; ++mi)
        af[mi] = *(const bf16x8*)&As[(wr * 32 + mi * 16 + l15) * 40 + lk8];
      #pragma unroll
      for (int ni = 0; ni < 2; ++ni)
        bfr[ni] = *(const bf16x8*)&Bs[(wc * 32 + ni * 16 + l15) * 40 + lk8];
      #pragma unroll
      for (int mi = 0; mi < 2; ++mi)
        #pragma unroll
        for (int ni = 0; ni < 2; ++ni)
          acc[mi][ni] = __builtin_amdgcn_mfma_f32_16x16x32_bf16(
              af[mi], bfr[ni], acc[mi][ni], 0, 0, 0);
      __syncthreads();
    }

    #pragma unroll
    for (int mi = 0; mi < 2; ++mi) {
      #pragma unroll
      for (int ni = 0; ni < 2; ++ni) {
        #pragma unroll
        for (int r = 0; r < 4; ++r) {
          int grow = row0 + wr * 32 + mi * 16 + (lane >> 4) * 4 + r;
          int gcol = col0 + wc * 32 + ni * 16 + l15;
          if (grow < M) h1[(size_t)grow * F1 + gcol] = f2fp8(acc[mi][ni][r]);
        }
      }
    }
  } else if (bid < GB1 + FB) {
    int e = (bid - GB1) * 256 + tid;
    if (e >= Etot) return;
    int s, d;
    if (e < E0) { s = ei[e]; d = ei[E0 + e]; } else { s = d = e - E0; }
    int slot = row_start[d] + atomicAdd(&cursor[d], 1);
    csr_src[slot] = s;
  } else {
    float* ws = (float*)smem;
    float* wd = ws + 1024;
    #pragma unroll
    for (int i = 0; i < 4; ++i) {
      ws[tid + i * 256] = Wsrc[tid + i * 256];
      wd[tid + i * 256] = Wdst[tid + i * 256];
    }
    __syncthreads();
    const int node = (bid - GB1 - FB) * 32 + (tid >> 3);
    const int h = tid & 7;
    if (node >= M) return;
    float as = 0.f, ad = 0.f;
    const float* xr = &x[(size_t)node * 128];
    for (int k = 0; k < 128; ++k) {
      float xv = xr[k];
      as += xv * ws[k * 8 + h];
      ad += xv * wd[k * 8 + h];
    }
    a_src[node * 8 + h] = as;
    a_dst[node * 8 + h] = ad;
  }
}

// -------------------------- MFMA GEMM (layer 2) -----------------------------
__global__ __launch_bounds__(256) void gemm_bf16(
    const ushort_t* __restrict__ Ab, const ushort_t* __restrict__ Bt,
    ushort_t* __restrict__ Cb, int M, int N, int K) {
  __shared__ ushort_t As[64 * 40];
  __shared__ ushort_t Bs[64 * 40];
  const int tid = threadIdx.x;
  const int lane = tid & 63;
  const int wave = tid >> 6;
  const int wr = wave >> 1, wc = wave & 1;
  const int row0 = blockIdx.y * 64, col0 = blockIdx.x * 64;
  const int sr = tid >> 2;
  const int sk = (tid & 3) * 8;
  const int l15 = lane & 15;
  const int lk8 = (lane >> 4) * 8;

  f32x4 acc[2][2];
  #pragma unroll
  for (int i = 0; i < 2; ++i)
    #pragma unroll
    for (int j = 0; j < 2; ++j) acc[i][j] = (f32x4){0.f, 0.f, 0.f, 0.f};

  for (int k0 = 0; k0 < K; k0 += 32) {
    const int gr = row0 + sr;
    uint4 av = {0u, 0u, 0u, 0u};
    if (gr < M) av = *(const uint4*)&Ab[(size_t)gr * K + k0 + sk];
    *(uint4*)&As[sr * 40 + sk] = av;
    uint4 bv = *(const uint4*)&Bt[(size_t)(col0 + sr) * K + k0 + sk];
    *(uint4*)&Bs[sr * 40 + sk] = bv;
    __syncthreads();

    bf16x8 af[2], bfr[2];
    #pragma unroll
    for (int mi = 0; mi < 2; ++mi)
      af[mi] = *(const bf16x8*)&As[(wr * 32 + mi * 16 + l15) * 40 + lk8];
    #pragma unroll
    for (int ni = 0; ni < 2; ++ni)
      bfr[ni] = *(const bf16x8*)&Bs[(wc * 32 + ni * 16 + l15) * 40 + lk8];
    #pragma unroll
    for (int mi = 0; mi < 2; ++mi)
      #pragma unroll
      for (int ni = 0; ni < 2; ++ni)
        acc[mi][ni] = __builtin_amdgcn_mfma_f32_16x16x32_bf16(
            af[mi], bfr[ni], acc[mi][ni], 0, 0, 0);
    __syncthreads();
  }

  #pragma unroll
  for (int mi = 0; mi < 2; ++mi) {
    #pragma unroll
    for (int ni = 0; ni < 2; ++ni) {
      #pragma unroll
      for (int r = 0; r < 4; ++r) {
        int grow = row0 + wr * 32 + mi * 16 + (lane >> 4) * 4 + r;
        int gcol = col0 + wc * 32 + ni * 16 + l15;
        if (grow < M) Cb[(size_t)grow * N + gcol] = f2bf(acc[mi][ni][r]);
      }
    }
  }
}

// ------- gather layer 1: wave-per-node, packed fp8 decode, uniform shfl -----
__global__ __launch_bounds__(256) void gather1(
    const int* __restrict__ csr_src, const int* __restrict__ row_start,
    const float* __restrict__ a_src, const float* __restrict__ a_dst,
    const uchar_t* __restrict__ h1, const float* __restrict__ b,
    const float* __restrict__ ws2, const float* __restrict__ wd2,
    ushort_t* __restrict__ out, float* __restrict__ a_src2,
    float* __restrict__ a_dst2, int n) {
  const int d = blockIdx.x * 4 + (threadIdx.x >> 6);
  const int lane = threadIdx.x & 63;
  if (d >= n) return;
  const int rs = row_start[d];
  const int deg = row_start[d + 1] - rs;
  const int pe = lane >> 3;
  const int ph = lane & 7;
  const int hsel = lane >> 3;
  const float adv = a_dst[d * 8 + ph];

  float dpart = 0.f;
  f32x4 acc = {0.f, 0.f, 0.f, 0.f};

  for (int t0 = 0; t0 < deg; t0 += 8) {
    const int nt = min(8, deg - t0);
    const int myi = t0 + pe;
    int mys = 0;
    float myc = 0.f;
    if (myi < deg) {
      mys = csr_src[rs + myi];
      myc = __expf(lrelu(a_src[mys * 8 + ph] + adv));
      dpart += myc;
    }
    for (int jj = 0; jj < nt; ++jj) {
      float cf = __shfl(myc, jj * 8 + hsel, 64);
      int s = __shfl(mys, jj * 8, 64);
      uint hv = *(const uint*)&h1[(size_t)s * F1 + lane * 4];
      f32x4 hd = fp8x4_decode(hv);
      acc[0] += cf * hd[0];
      acc[1] += cf * hd[1];
      acc[2] += cf * hd[2];
      acc[3] += cf * hd[3];
    }
  }

  dpart += __shfl_xor(dpart, 8, 64);
  dpart += __shfl_xor(dpart, 16, 64);
  dpart += __shfl_xor(dpart, 32, 64);
  const float rden = 1.f / __shfl(dpart, hsel, 64);

  const int ch = lane * 4;
  ushort4 ob;
  float ps = 0.f, pd = 0.f;
  #pragma unroll
  for (int j = 0; j < 4; ++j) {
    float v = fmaxf(acc[j] * rden + b[ch + j], 0.f);
    ushort_t bv = f2bf(v);
    ((ushort_t*)&ob)[j] = bv;
    float r = bf2f(bv);
    ps += r * ws2[ch + j];
    pd += r * wd2[ch + j];
  }
  *(ushort4*)&out[(size_t)d * F1 + ch] = ob;
  #pragma unroll
  for (int off = 32; off > 0; off >>= 1) {
    ps += __shfl_xor(ps, off, 64);
    pd += __shfl_xor(pd, off, 64);
  }
  if (lane == 0) {
    a_src2[d] = ps;
    a_dst2[d] = pd;
  }
}

// ------ gather layer 2 + log_softmax: 4-edge-parallel, UNIFORM trip count ---
__global__ __launch_bounds__(256) void gather2(
    const int* __restrict__ csr_src, const int* __restrict__ row_start,
    const float* __restrict__ a_src, const float* __restrict__ a_dst,
    const ushort_t* __restrict__ h2, const float* __restrict__ b,
    float* __restrict__ out, int n) {
  const int d = blockIdx.x * 4 + (threadIdx.x >> 6);
  const int lane = threadIdx.x & 63;
  if (d >= n) return;
  const int rs = row_start[d];
  const int deg = row_start[d + 1] - rs;
  const float adv = a_dst[d];

  const int sub = lane >> 4;
  const int q = lane & 15;
  float lsum = 0.f;
  f32x4 acc = {0.f, 0.f, 0.f, 0.f};
  for (int t0 = 0; t0 < deg; t0 += 64) {
    int myi = t0 + lane;
    int mys = 0;
    float myc = 0.f;
    if (myi < deg) {
      mys = csr_src[rs + myi];
      myc = __expf(lrelu(a_src[mys] + adv));
      lsum += myc;
    }
    const int nt = min(64, deg - t0);
    const int ntp = (nt + 3) & ~3;
    for (int e = sub; e < ntp; e += 4) {
      float cf = __shfl(myc, e, 64);
      int s = __shfl(mys, e, 64);
      ushort4 hv = *(const ushort4*)&h2[(size_t)s * F2 + q * 4];
      acc[0] += cf * bf2f(hv.x);
      acc[1] += cf * bf2f(hv.y);
      acc[2] += cf * bf2f(hv.z);
      acc[3] += cf * bf2f(hv.w);
    }
  }
  #pragma unroll
  for (int off = 32; off > 0; off >>= 1) lsum += __shfl_xor(lsum, off, 64);
  const float rden = 1.f / lsum;

  #pragma unroll
  for (int j = 0; j < 4; ++j) {
    acc[j] += __shfl_xor(acc[j], 16, 64);
    acc[j] += __shfl_xor(acc[j], 32, 64);
  }
  float vx = __shfl(acc[0], lane >> 2, 64);
  float vy = __shfl(acc[1], lane >> 2, 64);
  float vz = __shfl(acc[2], lane >> 2, 64);
  float vw = __shfl(acc[3], lane >> 2, 64);
  int c3 = lane & 3;
  float v = (c3 == 0) ? vx : (c3 == 1) ? vy : (c3 == 2) ? vz : vw;
  v = v * rden + b[lane];
  float m = v;
  #pragma unroll
  for (int off = 32; off > 0; off >>= 1) m = fmaxf(m, __shfl_xor(m, off, 64));
  float ex = __expf(v - m);
  float ss = ex;
  #pragma unroll
  for (int off = 32; off > 0; off >>= 1) ss += __shfl_xor(ss, off, 64);
  out[(size_t)d * F2 + lane] = v - m - __logf(ss);
}

// ------------------------------- launch -------------------------------------
extern "C" void kernel_launch(void* const* d_in, const int* in_sizes, int n_in,
                              void* d_out, int out_size, void* d_ws,
                              size_t ws_size, hipStream_t stream) {
  const float* x        = (const float*)d_in[0];
  const int*   ei       = (const int*)d_in[1];
  const float* W1       = (const float*)d_in[2];
  const float* att_src1 = (const float*)d_in[3];
  const float* att_dst1 = (const float*)d_in[4];
  const float* b1       = (const float*)d_in[5];
  const float* W2       = (const float*)d_in[6];
  const float* att_src2 = (const float*)d_in[7];
  const float* att_dst2 = (const float*)d_in[8];
  const float* b2       = (const float*)d_in[9];

  const int N = in_sizes[0] / 128;
  const int E0 = in_sizes[1] / 2;
  const int Etot = E0 + N;
  const int nb1024 = (N + 1023) / 1024;

  char* w = (char*)d_ws;
  size_t off = 0;
  auto alloc = [&](size_t bytes) {
    char* p = w + off;
    off += (bytes + 255) & ~(size_t)255;
    return p;
  };
  uchar_t*  h1        = (uchar_t*) alloc((size_t)N * F1 * 1);
  ushort_t* h1out     = (ushort_t*)alloc((size_t)N * F1 * 2);
  ushort_t* h2b       = (ushort_t*)alloc((size_t)N * F2 * 2);
  int*      csr_src   = (int*)     alloc((size_t)Etot * 4);
  int*      row_start = (int*)     alloc((size_t)(N + 1) * 4);
  int*      cc        = (int*)     alloc(((size_t)2 * N + nb1024) * 4);
  int*      counts    = cc;
  int*      cursor    = cc + N;
  int*      btot      = cc + 2 * N;
  float*    a_src1    = (float*)   alloc((size_t)N * HEADS1 * 4);
  float*    a_dst1    = (float*)   alloc((size_t)N * HEADS1 * 4);
  float*    a_src2    = (float*)   alloc((size_t)N * 4);
  float*    a_dst2    = (float*)   alloc((size_t)N * 4);
  ushort_t* W1t       = (ushort_t*)alloc(128 * 256 * 2);
  ushort_t* W2t       = (ushort_t*)alloc(256 * 64 * 2);
  float*    Wsrc1     = (float*)   alloc(128 * 8 * 4);
  float*    Wdst1     = (float*)   alloc(128 * 8 * 4);
  float*    w_s2      = (float*)   alloc(256 * 4);
  float*    w_d2      = (float*)   alloc(256 * 4);

  hipMemsetAsync(cc, 0, ((size_t)2 * N + nb1024) * 4, stream);

  dim3 blk(256);
  const int eb = (Etot + 255) / 256;
  const int gy = (N + 63) / 64;
  const int GB1 = 4 * gy;
  const int attb = (N + 31) / 32;

  kernelA<<<197 + eb, blk, 0, stream>>>(W1, W2, att_src1, att_dst1, att_src2,
                                        att_dst2, W1t, W2t, Wsrc1, Wdst1,
                                        w_s2, w_d2, ei, E0, Etot, counts);
  scan_fused<<<nb1024, blk, 0, stream>>>(counts, row_start, btot, N);

  kernelB<<<GB1 + eb + attb, blk, 0, stream>>>(
      x, W1t, h1, N, ei, E0, Etot, row_start, cursor, csr_src, Wsrc1, Wdst1,
      a_src1, a_dst1, GB1, eb);

  gather1<<<(N + 3) / 4, blk, 0, stream>>>(csr_src, row_start, a_src1, a_dst1,
                                           h1, b1, w_s2, w_d2, h1out, a_src2,
                                           a_dst2, N);

  gemm_bf16<<<dim3(F2 / 64, gy), blk, 0, stream>>>(h1out, W2t, h2b, N, F2, F1);
  gather2<<<(N + 3) / 4, blk, 0, stream>>>(csr_src, row_start, a_src2, a_dst2,
                                           h2b, b2, (float*)d_out, N);
}

// Round 20
// 223.618 us; speedup vs baseline: 1.0438x; 1.0438x over previous
//
#include <hip/hip_runtime.h>
#include <hip/hip_bf16.h>
#include <hip/hip_fp8.h>
#include <cmath>

// ---------------------------------------------------------------------------
// GAT 2-layer forward. R20: attproj1 folded into gemm1 as extra B columns
// (W1ext[320][128]: 256 output ch + 8 src-proj + 8 dst-proj + 48 pad).
// kernelB = widened gemm1 + fill_csr. Everything else identical to R19.
// ---------------------------------------------------------------------------

#define HEADS1 8
#define F1 256
#define F2 64
#define NEG_SLOPE 0.2f

typedef unsigned int uint;
typedef unsigned short ushort_t;
typedef unsigned char uchar_t;
typedef __attribute__((ext_vector_type(8))) short bf16x8;
typedef __attribute__((ext_vector_type(4))) float f32x4;
typedef __attribute__((ext_vector_type(2))) float f32x2;

__device__ __forceinline__ float lrelu(float x) {
  return x >= 0.f ? x : NEG_SLOPE * x;
}
__device__ __forceinline__ ushort_t f2bf(float f) {
  uint u = __float_as_uint(f);
  return (ushort_t)((u + 0x7FFFu + ((u >> 16) & 1u)) >> 16);
}
__device__ __forceinline__ float bf2f(ushort_t u) {
  return __uint_as_float(((uint)u) << 16);
}
__device__ __forceinline__ uint pack2(float a, float b) {
  return (uint)f2bf(a) | ((uint)f2bf(b) << 16);
}
__device__ __forceinline__ uchar_t f2fp8(float f) {
  __hip_fp8_e4m3 t(f);
  return (uchar_t)t.__x;
}
__device__ __forceinline__ float fp82f(uchar_t u) {
  __hip_fp8_e4m3 t;
  t.__x = (__hip_fp8_storage_t)u;
  return (float)t;
}
__device__ __forceinline__ f32x4 fp8x4_decode(uint hv) {
#if __has_builtin(__builtin_amdgcn_cvt_pk_f32_fp8)
  f32x2 lo = __builtin_amdgcn_cvt_pk_f32_fp8((int)hv, false);
  f32x2 hi = __builtin_amdgcn_cvt_pk_f32_fp8((int)hv, true);
  return (f32x4){lo.x, lo.y, hi.x, hi.y};
#else
  return (f32x4){fp82f((uchar_t)(hv & 0xff)),
                 fp82f((uchar_t)((hv >> 8) & 0xff)),
                 fp82f((uchar_t)((hv >> 16) & 0xff)),
                 fp82f((uchar_t)(hv >> 24))};
#endif
}

// --- kernel A: W1ext (320 rows) + W2t + w_s2/w_d2 + deg_count --------------
// blocks [0,128): W1ext rows 0..255 (transpose of W1)
// blocks [128,192): W2t
// blocks [192,200): W1ext rows 256..271 (att projections, bf16)
// blocks [200,224): W1ext rows 272..319 zero
// block  224: w_s2/w_d2
// blocks [225,...): deg_count
__global__ __launch_bounds__(256) void kernelA(
    const float* __restrict__ W1, const float* __restrict__ W2,
    const float* __restrict__ att_src1, const float* __restrict__ att_dst1,
    const float* __restrict__ att_src2, const float* __restrict__ att_dst2,
    ushort_t* __restrict__ W1ext, ushort_t* __restrict__ W2t,
    float* __restrict__ w_s2, float* __restrict__ w_d2,
    const int* __restrict__ ei, int E0, int Etot, int* __restrict__ counts) {
  const int bid = blockIdx.x;
  const int tid = threadIdx.x;
  if (bid < 128) {
    int idx = bid * 256 + tid;
    int r = idx >> 8, c = idx & 255;
    W1ext[(size_t)c * 128 + r] = f2bf(W1[idx]);
  } else if (bid < 192) {
    int idx = (bid - 128) * 256 + tid;
    int r = idx >> 6, c = idx & 63;
    W2t[(size_t)c * 256 + r] = f2bf(W2[idx]);
  } else if (bid < 200) {
    int idx = (bid - 192) * 256 + tid;   // 0..2047
    int r16 = idx >> 7;                  // 0..15
    int k = idx & 127;
    const float* att = (r16 < 8) ? att_src1 : att_dst1;
    int h = r16 & 7;
    float v = 0.f;
    #pragma unroll
    for (int c = 0; c < 32; ++c)
      v += W1[(size_t)k * 256 + h * 32 + c] * att[h * 32 + c];
    W1ext[(size_t)(256 + r16) * 128 + k] = f2bf(v);
  } else if (bid < 224) {
    int idx = (bid - 200) * 256 + tid;   // 0..6143
    W1ext[(size_t)272 * 128 + idx] = 0;
  } else if (bid < 225) {
    int k = tid;
    float as = 0.f, ad = 0.f;
    #pragma unroll
    for (int c = 0; c < 64; ++c) {
      float wv = W2[(size_t)k * 64 + c];
      as += wv * att_src2[c];
      ad += wv * att_dst2[c];
    }
    w_s2[k] = as;
    w_d2[k] = ad;
  } else {
    int e = (bid - 225) * 256 + tid;
    if (e >= Etot) return;
    int d = (e < E0) ? ei[E0 + e] : (e - E0);
    atomicAdd(&counts[d], 1);
  }
}

// ------------- fused exclusive scan: decoupled lookback, 1 kernel -----------
__global__ __launch_bounds__(256) void scan_fused(
    const int* __restrict__ counts, int* __restrict__ row_start,
    int* __restrict__ btot, int n) {
  __shared__ int wsum[4];
  __shared__ int s_prev;
  const int tid = threadIdx.x;
  const int lane = tid & 63;
  const int wid = tid >> 6;
  const int base = blockIdx.x * 1024 + tid * 4;
  int c[4], inc[4];
  #pragma unroll
  for (int j = 0; j < 4; ++j)
    c[j] = (base + j < n) ? counts[base + j] : 0;
  inc[0] = c[0];
  #pragma unroll
  for (int j = 1; j < 4; ++j) inc[j] = inc[j - 1] + c[j];
  int tsum = inc[3];
  int wincl = tsum;
  #pragma unroll
  for (int off = 1; off < 64; off <<= 1) {
    int v = __shfl_up(wincl, off, 64);
    if (lane >= off) wincl += v;
  }
  if (lane == 63) wsum[wid] = wincl;
  __syncthreads();
  int woff = 0;
  #pragma unroll
  for (int j = 0; j < 4; ++j)
    if (j < wid) woff += wsum[j];

  if (tid == 255) atomicExch(&btot[blockIdx.x], woff + wincl);

  if (wid == 0) {
    int run = 0;
    if (lane < blockIdx.x) {
      int v;
      do {
        v = atomicAdd(&btot[lane], 0);
      } while (v == 0);
      run = v;
    }
    #pragma unroll
    for (int off = 32; off > 0; off >>= 1) run += __shfl_xor(run, off, 64);
    if (lane == 0) s_prev = run;
  }
  __syncthreads();

  int prefix = s_prev + woff + (wincl - tsum);
  #pragma unroll
  for (int j = 0; j < 4; ++j)
    if (base + j < n) row_start[base + j + 1] = prefix + inc[j];
  if (blockIdx.x == 0 && tid == 0) row_start[0] = 0;
}

// ------- kernel B: widened gemm1 (5 col-tiles, proj epilogue) + fill_csr ----
__global__ __launch_bounds__(256) void kernelB(
    const float* __restrict__ x, const ushort_t* __restrict__ W1ext,
    uchar_t* __restrict__ h1, int M,
    const int* __restrict__ ei, int E0, int Etot,
    const int* __restrict__ row_start, int* __restrict__ cursor,
    int* __restrict__ csr_src,
    float* __restrict__ a_src, float* __restrict__ a_dst,
    int GB1) {
  __shared__ char smem[10240];
  const int bid = blockIdx.x;
  const int tid = threadIdx.x;

  if (bid < GB1) {
    ushort_t* As = (ushort_t*)smem;
    ushort_t* Bs = As + 64 * 40;
    const int lane = tid & 63;
    const int wave = tid >> 6;
    const int wr = wave >> 1, wc = wave & 1;
    const int ct = bid % 5;               // column tile 0..4
    const int row0 = (bid / 5) * 64, col0 = ct * 64;
    const int sr = tid >> 2;
    const int sk = (tid & 3) * 8;
    const int l15 = lane & 15;
    const int lk8 = (lane >> 4) * 8;
    const int K = 128;

    f32x4 acc[2][2];
    #pragma unroll
    for (int i = 0; i < 2; ++i)
      #pragma unroll
      for (int j = 0; j < 2; ++j) acc[i][j] = (f32x4){0.f, 0.f, 0.f, 0.f};

    for (int k0 = 0; k0 < K; k0 += 32) {
      const int gr = row0 + sr;
      float4 f0 = {0.f, 0.f, 0.f, 0.f}, f1 = {0.f, 0.f, 0.f, 0.f};
      if (gr < M) {
        f0 = *(const float4*)&x[(size_t)gr * K + k0 + sk];
        f1 = *(const float4*)&x[(size_t)gr * K + k0 + sk + 4];
      }
      uint4 av;
      av.x = pack2(f0.x, f0.y);
      av.y = pack2(f0.z, f0.w);
      av.z = pack2(f1.x, f1.y);
      av.w = pack2(f1.z, f1.w);
      *(uint4*)&As[sr * 40 + sk] = av;
      uint4 bv = *(const uint4*)&W1ext[(size_t)(col0 + sr) * K + k0 + sk];
      *(uint4*)&Bs[sr * 40 + sk] = bv;
      __syncthreads();

      bf16x8 af[2], bfr[2];
      #pragma unroll
      for (int mi = 0; mi < 2; ++mi)
        af[mi] = *(const bf16x8*)&As[(wr * 32 + mi * 16 + l15) * 40 + lk8];
      #pragma unroll
      for (int ni = 0; ni < 2; ++ni)
        bfr[ni] = *(const bf16x8*)&Bs[(wc * 32 + ni * 16 + l15) * 40 + lk8];
      #pragma unroll
      for (int mi = 0; mi < 2; ++mi)
        #pragma unroll
        for (int ni = 0; ni < 2; ++ni)
          acc[mi][ni] = __builtin_amdgcn_mfma_f32_16x16x32_bf16(
              af[mi], bfr[ni], acc[mi][ni], 0, 0, 0);
      __syncthreads();
    }

    #pragma unroll
    for (int mi = 0; mi < 2; ++mi) {
      #pragma unroll
      for (int ni = 0; ni < 2; ++ni) {
        #pragma unroll
        for (int r = 0; r < 4; ++r) {
          int grow = row0 + wr * 32 + mi * 16 + (lane >> 4) * 4 + r;
          int gcol = col0 + wc * 32 + ni * 16 + l15;
          if (grow >= M) continue;
          float v = acc[mi][ni][r];
          if (gcol < 256) {
            h1[(size_t)grow * F1 + gcol] = f2fp8(v);
          } else if (gcol < 264) {
            a_src[(size_t)grow * 8 + (gcol - 256)] = v;
          } else if (gcol < 272) {
            a_dst[(size_t)grow * 8 + (gcol - 264)] = v;
          }
        }
      }
    }
  } else {
    int e = (bid - GB1) * 256 + tid;
    if (e >= Etot) return;
    int s, d;
    if (e < E0) { s = ei[e]; d = ei[E0 + e]; } else { s = d = e - E0; }
    int slot = row_start[d] + atomicAdd(&cursor[d], 1);
    csr_src[slot] = s;
  }
}

// -------------------------- MFMA GEMM (layer 2) -----------------------------
__global__ __launch_bounds__(256) void gemm_bf16(
    const ushort_t* __restrict__ Ab, const ushort_t* __restrict__ Bt,
    ushort_t* __restrict__ Cb, int M, int N, int K) {
  __shared__ ushort_t As[64 * 40];
  __shared__ ushort_t Bs[64 * 40];
  const int tid = threadIdx.x;
  const int lane = tid & 63;
  const int wave = tid >> 6;
  const int wr = wave >> 1, wc = wave & 1;
  const int row0 = blockIdx.y * 64, col0 = blockIdx.x * 64;
  const int sr = tid >> 2;
  const int sk = (tid & 3) * 8;
  const int l15 = lane & 15;
  const int lk8 = (lane >> 4) * 8;

  f32x4 acc[2][2];
  #pragma unroll
  for (int i = 0; i < 2; ++i)
    #pragma unroll
    for (int j = 0; j < 2; ++j) acc[i][j] = (f32x4){0.f, 0.f, 0.f, 0.f};

  for (int k0 = 0; k0 < K; k0 += 32) {
    const int gr = row0 + sr;
    uint4 av = {0u, 0u, 0u, 0u};
    if (gr < M) av = *(const uint4*)&Ab[(size_t)gr * K + k0 + sk];
    *(uint4*)&As[sr * 40 + sk] = av;
    uint4 bv = *(const uint4*)&Bt[(size_t)(col0 + sr) * K + k0 + sk];
    *(uint4*)&Bs[sr * 40 + sk] = bv;
    __syncthreads();

    bf16x8 af[2], bfr[2];
    #pragma unroll
    for (int mi = 0; mi < 2; ++mi)
      af[mi] = *(const bf16x8*)&As[(wr * 32 + mi * 16 + l15) * 40 + lk8];
    #pragma unroll
    for (int ni = 0; ni < 2; ++ni)
      bfr[ni] = *(const bf16x8*)&Bs[(wc * 32 + ni * 16 + l15) * 40 + lk8];
    #pragma unroll
    for (int mi = 0; mi < 2; ++mi)
      #pragma unroll
      for (int ni = 0; ni < 2; ++ni)
        acc[mi][ni] = __builtin_amdgcn_mfma_f32_16x16x32_bf16(
            af[mi], bfr[ni], acc[mi][ni], 0, 0, 0);
    __syncthreads();
  }

  #pragma unroll
  for (int mi = 0; mi < 2; ++mi) {
    #pragma unroll
    for (int ni = 0; ni < 2; ++ni) {
      #pragma unroll
      for (int r = 0; r < 4; ++r) {
        int grow = row0 + wr * 32 + mi * 16 + (lane >> 4) * 4 + r;
        int gcol = col0 + wc * 32 + ni * 16 + l15;
        if (grow < M) Cb[(size_t)grow * N + gcol] = f2bf(acc[mi][ni][r]);
      }
    }
  }
}

// ------- gather layer 1: wave-per-node, packed fp8 decode, uniform shfl -----
__global__ __launch_bounds__(256) void gather1(
    const int* __restrict__ csr_src, const int* __restrict__ row_start,
    const float* __restrict__ a_src, const float* __restrict__ a_dst,
    const uchar_t* __restrict__ h1, const float* __restrict__ b,
    const float* __restrict__ ws2, const float* __restrict__ wd2,
    ushort_t* __restrict__ out, float* __restrict__ a_src2,
    float* __restrict__ a_dst2, int n) {
  const int d = blockIdx.x * 4 + (threadIdx.x >> 6);
  const int lane = threadIdx.x & 63;
  if (d >= n) return;
  const int rs = row_start[d];
  const int deg = row_start[d + 1] - rs;
  const int pe = lane >> 3;
  const int ph = lane & 7;
  const int hsel = lane >> 3;
  const float adv = a_dst[d * 8 + ph];

  float dpart = 0.f;
  f32x4 acc = {0.f, 0.f, 0.f, 0.f};

  for (int t0 = 0; t0 < deg; t0 += 8) {
    const int nt = min(8, deg - t0);
    const int myi = t0 + pe;
    int mys = 0;
    float myc = 0.f;
    if (myi < deg) {
      mys = csr_src[rs + myi];
      myc = __expf(lrelu(a_src[mys * 8 + ph] + adv));
      dpart += myc;
    }
    for (int jj = 0; jj < nt; ++jj) {
      float cf = __shfl(myc, jj * 8 + hsel, 64);
      int s = __shfl(mys, jj * 8, 64);
      uint hv = *(const uint*)&h1[(size_t)s * F1 + lane * 4];
      f32x4 hd = fp8x4_decode(hv);
      acc[0] += cf * hd[0];
      acc[1] += cf * hd[1];
      acc[2] += cf * hd[2];
      acc[3] += cf * hd[3];
    }
  }

  dpart += __shfl_xor(dpart, 8, 64);
  dpart += __shfl_xor(dpart, 16, 64);
  dpart += __shfl_xor(dpart, 32, 64);
  const float rden = 1.f / __shfl(dpart, hsel, 64);

  const int ch = lane * 4;
  ushort4 ob;
  float ps = 0.f, pd = 0.f;
  #pragma unroll
  for (int j = 0; j < 4; ++j) {
    float v = fmaxf(acc[j] * rden + b[ch + j], 0.f);
    ushort_t bv = f2bf(v);
    ((ushort_t*)&ob)[j] = bv;
    float r = bf2f(bv);
    ps += r * ws2[ch + j];
    pd += r * wd2[ch + j];
  }
  *(ushort4*)&out[(size_t)d * F1 + ch] = ob;
  #pragma unroll
  for (int off = 32; off > 0; off >>= 1) {
    ps += __shfl_xor(ps, off, 64);
    pd += __shfl_xor(pd, off, 64);
  }
  if (lane == 0) {
    a_src2[d] = ps;
    a_dst2[d] = pd;
  }
}

// ------ gather layer 2 + log_softmax: 4-edge-parallel, UNIFORM trip count ---
__global__ __launch_bounds__(256) void gather2(
    const int* __restrict__ csr_src, const int* __restrict__ row_start,
    const float* __restrict__ a_src, const float* __restrict__ a_dst,
    const ushort_t* __restrict__ h2, const float* __restrict__ b,
    float* __restrict__ out, int n) {
  const int d = blockIdx.x * 4 + (threadIdx.x >> 6);
  const int lane = threadIdx.x & 63;
  if (d >= n) return;
  const int rs = row_start[d];
  const int deg = row_start[d + 1] - rs;
  const float adv = a_dst[d];

  const int sub = lane >> 4;
  const int q = lane & 15;
  float lsum = 0.f;
  f32x4 acc = {0.f, 0.f, 0.f, 0.f};
  for (int t0 = 0; t0 < deg; t0 += 64) {
    int myi = t0 + lane;
    int mys = 0;
    float myc = 0.f;
    if (myi < deg) {
      mys = csr_src[rs + myi];
      myc = __expf(lrelu(a_src[mys] + adv));
      lsum += myc;
    }
    const int nt = min(64, deg - t0);
    const int ntp = (nt + 3) & ~3;
    for (int e = sub; e < ntp; e += 4) {
      float cf = __shfl(myc, e, 64);
      int s = __shfl(mys, e, 64);
      ushort4 hv = *(const ushort4*)&h2[(size_t)s * F2 + q * 4];
      acc[0] += cf * bf2f(hv.x);
      acc[1] += cf * bf2f(hv.y);
      acc[2] += cf * bf2f(hv.z);
      acc[3] += cf * bf2f(hv.w);
    }
  }
  #pragma unroll
  for (int off = 32; off > 0; off >>= 1) lsum += __shfl_xor(lsum, off, 64);
  const float rden = 1.f / lsum;

  #pragma unroll
  for (int j = 0; j < 4; ++j) {
    acc[j] += __shfl_xor(acc[j], 16, 64);
    acc[j] += __shfl_xor(acc[j], 32, 64);
  }
  float vx = __shfl(acc[0], lane >> 2, 64);
  float vy = __shfl(acc[1], lane >> 2, 64);
  float vz = __shfl(acc[2], lane >> 2, 64);
  float vw = __shfl(acc[3], lane >> 2, 64);
  int c3 = lane & 3;
  float v = (c3 == 0) ? vx : (c3 == 1) ? vy : (c3 == 2) ? vz : vw;
  v = v * rden + b[lane];
  float m = v;
  #pragma unroll
  for (int off = 32; off > 0; off >>= 1) m = fmaxf(m, __shfl_xor(m, off, 64));
  float ex = __expf(v - m);
  float ss = ex;
  #pragma unroll
  for (int off = 32; off > 0; off >>= 1) ss += __shfl_xor(ss, off, 64);
  out[(size_t)d * F2 + lane] = v - m - __logf(ss);
}

// ------------------------------- launch -------------------------------------
extern "C" void kernel_launch(void* const* d_in, const int* in_sizes, int n_in,
                              void* d_out, int out_size, void* d_ws,
                              size_t ws_size, hipStream_t stream) {
  const float* x        = (const float*)d_in[0];
  const int*   ei       = (const int*)d_in[1];
  const float* W1       = (const float*)d_in[2];
  const float* att_src1 = (const float*)d_in[3];
  const float* att_dst1 = (const float*)d_in[4];
  const float* b1       = (const float*)d_in[5];
  const float* W2       = (const float*)d_in[6];
  const float* att_src2 = (const float*)d_in[7];
  const float* att_dst2 = (const float*)d_in[8];
  const float* b2       = (const float*)d_in[9];

  const int N = in_sizes[0] / 128;
  const int E0 = in_sizes[1] / 2;
  const int Etot = E0 + N;
  const int nb1024 = (N + 1023) / 1024;

  char* w = (char*)d_ws;
  size_t off = 0;
  auto alloc = [&](size_t bytes) {
    char* p = w + off;
    off += (bytes + 255) & ~(size_t)255;
    return p;
  };
  uchar_t*  h1        = (uchar_t*) alloc((size_t)N * F1 * 1);
  ushort_t* h1out     = (ushort_t*)alloc((size_t)N * F1 * 2);
  ushort_t* h2b       = (ushort_t*)alloc((size_t)N * F2 * 2);
  int*      csr_src   = (int*)     alloc((size_t)Etot * 4);
  int*      row_start = (int*)     alloc((size_t)(N + 1) * 4);
  int*      cc        = (int*)     alloc(((size_t)2 * N + nb1024) * 4);
  int*      counts    = cc;
  int*      cursor    = cc + N;
  int*      btot      = cc + 2 * N;
  float*    a_src1    = (float*)   alloc((size_t)N * HEADS1 * 4);
  float*    a_dst1    = (float*)   alloc((size_t)N * HEADS1 * 4);
  float*    a_src2    = (float*)   alloc((size_t)N * 4);
  float*    a_dst2    = (float*)   alloc((size_t)N * 4);
  ushort_t* W1ext     = (ushort_t*)alloc(320 * 128 * 2);
  ushort_t* W2t       = (ushort_t*)alloc(256 * 64 * 2);
  float*    w_s2      = (float*)   alloc(256 * 4);
  float*    w_d2      = (float*)   alloc(256 * 4);

  hipMemsetAsync(cc, 0, ((size_t)2 * N + nb1024) * 4, stream);

  dim3 blk(256);
  const int eb = (Etot + 255) / 256;
  const int gy = (N + 63) / 64;
  const int GB1 = 5 * gy;   // widened gemm1: 5 column tiles

  kernelA<<<225 + eb, blk, 0, stream>>>(W1, W2, att_src1, att_dst1, att_src2,
                                        att_dst2, W1ext, W2t, w_s2, w_d2,
                                        ei, E0, Etot, counts);
  scan_fused<<<nb1024, blk, 0, stream>>>(counts, row_start, btot, N);

  kernelB<<<GB1 + eb, blk, 0, stream>>>(
      x, W1ext, h1, N, ei, E0, Etot, row_start, cursor, csr_src,
      a_src1, a_dst1, GB1);

  gather1<<<(N + 3) / 4, blk, 0, stream>>>(csr_src, row_start, a_src1, a_dst1,
                                           h1, b1, w_s2, w_d2, h1out, a_src2,
                                           a_dst2, N);

  gemm_bf16<<<dim3(F2 / 64, gy), blk, 0, stream>>>(h1out, W2t, h2b, N, F2, F1);
  gather2<<<(N + 3) / 4, blk, 0, stream>>>(csr_src, row_start, a_src2, a_dst2,
                                           h2b, b2, (float*)d_out, N);
}

// Round 21
// 195.387 us; speedup vs baseline: 1.1946x; 1.1445x over previous
//
#include <hip/hip_runtime.h>
#include <hip/hip_bf16.h>
#include <hip/hip_fp8.h>
#include <cmath>

// ---------------------------------------------------------------------------
// GAT 2-layer forward. R21: gather1 consumer loop made compile-time 8
// iterations (padding edges broadcast coef 0 -> exact), unlocking 8-deep
// memory-level parallelism on the row gathers. Everything else = R20.
// ---------------------------------------------------------------------------

#define HEADS1 8
#define F1 256
#define F2 64
#define NEG_SLOPE 0.2f

typedef unsigned int uint;
typedef unsigned short ushort_t;
typedef unsigned char uchar_t;
typedef __attribute__((ext_vector_type(8))) short bf16x8;
typedef __attribute__((ext_vector_type(4))) float f32x4;
typedef __attribute__((ext_vector_type(2))) float f32x2;

__device__ __forceinline__ float lrelu(float x) {
  return x >= 0.f ? x : NEG_SLOPE * x;
}
__device__ __forceinline__ ushort_t f2bf(float f) {
  uint u = __float_as_uint(f);
  return (ushort_t)((u + 0x7FFFu + ((u >> 16) & 1u)) >> 16);
}
__device__ __forceinline__ float bf2f(ushort_t u) {
  return __uint_as_float(((uint)u) << 16);
}
__device__ __forceinline__ uint pack2(float a, float b) {
  return (uint)f2bf(a) | ((uint)f2bf(b) << 16);
}
__device__ __forceinline__ uchar_t f2fp8(float f) {
  __hip_fp8_e4m3 t(f);
  return (uchar_t)t.__x;
}
__device__ __forceinline__ float fp82f(uchar_t u) {
  __hip_fp8_e4m3 t;
  t.__x = (__hip_fp8_storage_t)u;
  return (float)t;
}
__device__ __forceinline__ f32x4 fp8x4_decode(uint hv) {
#if __has_builtin(__builtin_amdgcn_cvt_pk_f32_fp8)
  f32x2 lo = __builtin_amdgcn_cvt_pk_f32_fp8((int)hv, false);
  f32x2 hi = __builtin_amdgcn_cvt_pk_f32_fp8((int)hv, true);
  return (f32x4){lo.x, lo.y, hi.x, hi.y};
#else
  return (f32x4){fp82f((uchar_t)(hv & 0xff)),
                 fp82f((uchar_t)((hv >> 8) & 0xff)),
                 fp82f((uchar_t)((hv >> 16) & 0xff)),
                 fp82f((uchar_t)(hv >> 24))};
#endif
}

// --- kernel A: W1ext (320 rows) + W2t + w_s2/w_d2 + deg_count --------------
__global__ __launch_bounds__(256) void kernelA(
    const float* __restrict__ W1, const float* __restrict__ W2,
    const float* __restrict__ att_src1, const float* __restrict__ att_dst1,
    const float* __restrict__ att_src2, const float* __restrict__ att_dst2,
    ushort_t* __restrict__ W1ext, ushort_t* __restrict__ W2t,
    float* __restrict__ w_s2, float* __restrict__ w_d2,
    const int* __restrict__ ei, int E0, int Etot, int* __restrict__ counts) {
  const int bid = blockIdx.x;
  const int tid = threadIdx.x;
  if (bid < 128) {
    int idx = bid * 256 + tid;
    int r = idx >> 8, c = idx & 255;
    W1ext[(size_t)c * 128 + r] = f2bf(W1[idx]);
  } else if (bid < 192) {
    int idx = (bid - 128) * 256 + tid;
    int r = idx >> 6, c = idx & 63;
    W2t[(size_t)c * 256 + r] = f2bf(W2[idx]);
  } else if (bid < 200) {
    int idx = (bid - 192) * 256 + tid;   // 0..2047
    int r16 = idx >> 7;                  // 0..15
    int k = idx & 127;
    const float* att = (r16 < 8) ? att_src1 : att_dst1;
    int h = r16 & 7;
    float v = 0.f;
    #pragma unroll
    for (int c = 0; c < 32; ++c)
      v += W1[(size_t)k * 256 + h * 32 + c] * att[h * 32 + c];
    W1ext[(size_t)(256 + r16) * 128 + k] = f2bf(v);
  } else if (bid < 224) {
    int idx = (bid - 200) * 256 + tid;   // 0..6143
    W1ext[(size_t)272 * 128 + idx] = 0;
  } else if (bid < 225) {
    int k = tid;
    float as = 0.f, ad = 0.f;
    #pragma unroll
    for (int c = 0; c < 64; ++c) {
      float wv = W2[(size_t)k * 64 + c];
      as += wv * att_src2[c];
      ad += wv * att_dst2[c];
    }
    w_s2[k] = as;
    w_d2[k] = ad;
  } else {
    int e = (bid - 225) * 256 + tid;
    if (e >= Etot) return;
    int d = (e < E0) ? ei[E0 + e] : (e - E0);
    atomicAdd(&counts[d], 1);
  }
}

// ------------- fused exclusive scan: decoupled lookback, 1 kernel -----------
__global__ __launch_bounds__(256) void scan_fused(
    const int* __restrict__ counts, int* __restrict__ row_start,
    int* __restrict__ btot, int n) {
  __shared__ int wsum[4];
  __shared__ int s_prev;
  const int tid = threadIdx.x;
  const int lane = tid & 63;
  const int wid = tid >> 6;
  const int base = blockIdx.x * 1024 + tid * 4;
  int c[4], inc[4];
  #pragma unroll
  for (int j = 0; j < 4; ++j)
    c[j] = (base + j < n) ? counts[base + j] : 0;
  inc[0] = c[0];
  #pragma unroll
  for (int j = 1; j < 4; ++j) inc[j] = inc[j - 1] + c[j];
  int tsum = inc[3];
  int wincl = tsum;
  #pragma unroll
  for (int off = 1; off < 64; off <<= 1) {
    int v = __shfl_up(wincl, off, 64);
    if (lane >= off) wincl += v;
  }
  if (lane == 63) wsum[wid] = wincl;
  __syncthreads();
  int woff = 0;
  #pragma unroll
  for (int j = 0; j < 4; ++j)
    if (j < wid) woff += wsum[j];

  if (tid == 255) atomicExch(&btot[blockIdx.x], woff + wincl);

  if (wid == 0) {
    int run = 0;
    if (lane < blockIdx.x) {
      int v;
      do {
        v = atomicAdd(&btot[lane], 0);
      } while (v == 0);
      run = v;
    }
    #pragma unroll
    for (int off = 32; off > 0; off >>= 1) run += __shfl_xor(run, off, 64);
    if (lane == 0) s_prev = run;
  }
  __syncthreads();

  int prefix = s_prev + woff + (wincl - tsum);
  #pragma unroll
  for (int j = 0; j < 4; ++j)
    if (base + j < n) row_start[base + j + 1] = prefix + inc[j];
  if (blockIdx.x == 0 && tid == 0) row_start[0] = 0;
}

// ------- kernel B: widened gemm1 (5 col-tiles, proj epilogue) + fill_csr ----
__global__ __launch_bounds__(256) void kernelB(
    const float* __restrict__ x, const ushort_t* __restrict__ W1ext,
    uchar_t* __restrict__ h1, int M,
    const int* __restrict__ ei, int E0, int Etot,
    const int* __restrict__ row_start, int* __restrict__ cursor,
    int* __restrict__ csr_src,
    float* __restrict__ a_src, float* __restrict__ a_dst,
    int GB1) {
  __shared__ char smem[10240];
  const int bid = blockIdx.x;
  const int tid = threadIdx.x;

  if (bid < GB1) {
    ushort_t* As = (ushort_t*)smem;
    ushort_t* Bs = As + 64 * 40;
    const int lane = tid & 63;
    const int wave = tid >> 6;
    const int wr = wave >> 1, wc = wave & 1;
    const int ct = bid % 5;
    const int row0 = (bid / 5) * 64, col0 = ct * 64;
    const int sr = tid >> 2;
    const int sk = (tid & 3) * 8;
    const int l15 = lane & 15;
    const int lk8 = (lane >> 4) * 8;
    const int K = 128;

    f32x4 acc[2][2];
    #pragma unroll
    for (int i = 0; i < 2; ++i)
      #pragma unroll
      for (int j = 0; j < 2; ++j) acc[i][j] = (f32x4){0.f, 0.f, 0.f, 0.f};

    for (int k0 = 0; k0 < K; k0 += 32) {
      const int gr = row0 + sr;
      float4 f0 = {0.f, 0.f, 0.f, 0.f}, f1 = {0.f, 0.f, 0.f, 0.f};
      if (gr < M) {
        f0 = *(const float4*)&x[(size_t)gr * K + k0 + sk];
        f1 = *(const float4*)&x[(size_t)gr * K + k0 + sk + 4];
      }
      uint4 av;
      av.x = pack2(f0.x, f0.y);
      av.y = pack2(f0.z, f0.w);
      av.z = pack2(f1.x, f1.y);
      av.w = pack2(f1.z, f1.w);
      *(uint4*)&As[sr * 40 + sk] = av;
      uint4 bv = *(const uint4*)&W1ext[(size_t)(col0 + sr) * K + k0 + sk];
      *(uint4*)&Bs[sr * 40 + sk] = bv;
      __syncthreads();

      bf16x8 af[2], bfr[2];
      #pragma unroll
      for (int mi = 0; mi < 2; ++mi)
        af[mi] = *(const bf16x8*)&As[(wr * 32 + mi * 16 + l15) * 40 + lk8];
      #pragma unroll
      for (int ni = 0; ni < 2; ++ni)
        bfr[ni] = *(const bf16x8*)&Bs[(wc * 32 + ni * 16 + l15) * 40 + lk8];
      #pragma unroll
      for (int mi = 0; mi < 2; ++mi)
        #pragma unroll
        for (int ni = 0; ni < 2; ++ni)
          acc[mi][ni] = __builtin_amdgcn_mfma_f32_16x16x32_bf16(
              af[mi], bfr[ni], acc[mi][ni], 0, 0, 0);
      __syncthreads();
    }

    #pragma unroll
    for (int mi = 0; mi < 2; ++mi) {
      #pragma unroll
      for (int ni = 0; ni < 2; ++ni) {
        #pragma unroll
        for (int r = 0; r < 4; ++r) {
          int grow = row0 + wr * 32 + mi * 16 + (lane >> 4) * 4 + r;
          int gcol = col0 + wc * 32 + ni * 16 + l15;
          if (grow >= M) continue;
          float v = acc[mi][ni][r];
          if (gcol < 256) {
            h1[(size_t)grow * F1 + gcol] = f2fp8(v);
          } else if (gcol < 264) {
            a_src[(size_t)grow * 8 + (gcol - 256)] = v;
          } else if (gcol < 272) {
            a_dst[(size_t)grow * 8 + (gcol - 264)] = v;
          }
        }
      }
    }
  } else {
    int e = (bid - GB1) * 256 + tid;
    if (e >= Etot) return;
    int s, d;
    if (e < E0) { s = ei[e]; d = ei[E0 + e]; } else { s = d = e - E0; }
    int slot = row_start[d] + atomicAdd(&cursor[d], 1);
    csr_src[slot] = s;
  }
}

// -------------------------- MFMA GEMM (layer 2) -----------------------------
__global__ __launch_bounds__(256) void gemm_bf16(
    const ushort_t* __restrict__ Ab, const ushort_t* __restrict__ Bt,
    ushort_t* __restrict__ Cb, int M, int N, int K) {
  __shared__ ushort_t As[64 * 40];
  __shared__ ushort_t Bs[64 * 40];
  const int tid = threadIdx.x;
  const int lane = tid & 63;
  const int wave = tid >> 6;
  const int wr = wave >> 1, wc = wave & 1;
  const int row0 = blockIdx.y * 64, col0 = blockIdx.x * 64;
  const int sr = tid >> 2;
  const int sk = (tid & 3) * 8;
  const int l15 = lane & 15;
  const int lk8 = (lane >> 4) * 8;

  f32x4 acc[2][2];
  #pragma unroll
  for (int i = 0; i < 2; ++i)
    #pragma unroll
    for (int j = 0; j < 2; ++j) acc[i][j] = (f32x4){0.f, 0.f, 0.f, 0.f};

  for (int k0 = 0; k0 < K; k0 += 32) {
    const int gr = row0 + sr;
    uint4 av = {0u, 0u, 0u, 0u};
    if (gr < M) av = *(const uint4*)&Ab[(size_t)gr * K + k0 + sk];
    *(uint4*)&As[sr * 40 + sk] = av;
    uint4 bv = *(const uint4*)&Bt[(size_t)(col0 + sr) * K + k0 + sk];
    *(uint4*)&Bs[sr * 40 + sk] = bv;
    __syncthreads();

    bf16x8 af[2], bfr[2];
    #pragma unroll
    for (int mi = 0; mi < 2; ++mi)
      af[mi] = *(const bf16x8*)&As[(wr * 32 + mi * 16 + l15) * 40 + lk8];
    #pragma unroll
    for (int ni = 0; ni < 2; ++ni)
      bfr[ni] = *(const bf16x8*)&Bs[(wc * 32 + ni * 16 + l15) * 40 + lk8];
    #pragma unroll
    for (int mi = 0; mi < 2; ++mi)
      #pragma unroll
      for (int ni = 0; ni < 2; ++ni)
        acc[mi][ni] = __builtin_amdgcn_mfma_f32_16x16x32_bf16(
            af[mi], bfr[ni], acc[mi][ni], 0, 0, 0);
    __syncthreads();
  }

  #pragma unroll
  for (int mi = 0; mi < 2; ++mi) {
    #pragma unroll
    for (int ni = 0; ni < 2; ++ni) {
      #pragma unroll
      for (int r = 0; r < 4; ++r) {
        int grow = row0 + wr * 32 + mi * 16 + (lane >> 4) * 4 + r;
        int gcol = col0 + wc * 32 + ni * 16 + l15;
        if (grow < M) Cb[(size_t)grow * N + gcol] = f2bf(acc[mi][ni][r]);
      }
    }
  }
}

// ------- gather layer 1: wave-per-node, FIXED 8-iter consumer (8x MLP) ------
__global__ __launch_bounds__(256) void gather1(
    const int* __restrict__ csr_src, const int* __restrict__ row_start,
    const float* __restrict__ a_src, const float* __restrict__ a_dst,
    const uchar_t* __restrict__ h1, const float* __restrict__ b,
    const float* __restrict__ ws2, const float* __restrict__ wd2,
    ushort_t* __restrict__ out, float* __restrict__ a_src2,
    float* __restrict__ a_dst2, int n) {
  const int d = blockIdx.x * 4 + (threadIdx.x >> 6);
  const int lane = threadIdx.x & 63;
  if (d >= n) return;
  const int rs = row_start[d];
  const int deg = row_start[d + 1] - rs;
  const int pe = lane >> 3;
  const int ph = lane & 7;
  const int hsel = lane >> 3;
  const float adv = a_dst[d * 8 + ph];

  float dpart = 0.f;
  f32x4 acc = {0.f, 0.f, 0.f, 0.f};

  for (int t0 = 0; t0 < deg; t0 += 8) {
    const int myi = t0 + pe;
    int mys = 0;
    float myc = 0.f;
    if (myi < deg) {
      mys = csr_src[rs + myi];
      myc = __expf(lrelu(a_src[mys * 8 + ph] + adv));
      dpart += myc;
    }
    // fixed 8 iterations: padding edges broadcast myc=0, mys=0 (row 0,
    // L1-hot, contributes exactly 0) -> compiler unrolls, 8 loads in flight
    #pragma unroll
    for (int jj = 0; jj < 8; ++jj) {
      float cf = __shfl(myc, jj * 8 + hsel, 64);
      int s = __shfl(mys, jj * 8, 64);
      uint hv = *(const uint*)&h1[(size_t)s * F1 + lane * 4];
      f32x4 hd = fp8x4_decode(hv);
      acc[0] += cf * hd[0];
      acc[1] += cf * hd[1];
      acc[2] += cf * hd[2];
      acc[3] += cf * hd[3];
    }
  }

  dpart += __shfl_xor(dpart, 8, 64);
  dpart += __shfl_xor(dpart, 16, 64);
  dpart += __shfl_xor(dpart, 32, 64);
  const float rden = 1.f / __shfl(dpart, hsel, 64);

  const int ch = lane * 4;
  ushort4 ob;
  float ps = 0.f, pd = 0.f;
  #pragma unroll
  for (int j = 0; j < 4; ++j) {
    float v = fmaxf(acc[j] * rden + b[ch + j], 0.f);
    ushort_t bv = f2bf(v);
    ((ushort_t*)&ob)[j] = bv;
    float r = bf2f(bv);
    ps += r * ws2[ch + j];
    pd += r * wd2[ch + j];
  }
  *(ushort4*)&out[(size_t)d * F1 + ch] = ob;
  #pragma unroll
  for (int off = 32; off > 0; off >>= 1) {
    ps += __shfl_xor(ps, off, 64);
    pd += __shfl_xor(pd, off, 64);
  }
  if (lane == 0) {
    a_src2[d] = ps;
    a_dst2[d] = pd;
  }
}

// ------ gather layer 2 + log_softmax: 4-edge-parallel, UNIFORM trip count ---
__global__ __launch_bounds__(256) void gather2(
    const int* __restrict__ csr_src, const int* __restrict__ row_start,
    const float* __restrict__ a_src, const float* __restrict__ a_dst,
    const ushort_t* __restrict__ h2, const float* __restrict__ b,
    float* __restrict__ out, int n) {
  const int d = blockIdx.x * 4 + (threadIdx.x >> 6);
  const int lane = threadIdx.x & 63;
  if (d >= n) return;
  const int rs = row_start[d];
  const int deg = row_start[d + 1] - rs;
  const float adv = a_dst[d];

  const int sub = lane >> 4;
  const int q = lane & 15;
  float lsum = 0.f;
  f32x4 acc = {0.f, 0.f, 0.f, 0.f};
  for (int t0 = 0; t0 < deg; t0 += 64) {
    int myi = t0 + lane;
    int mys = 0;
    float myc = 0.f;
    if (myi < deg) {
      mys = csr_src[rs + myi];
      myc = __expf(lrelu(a_src[mys] + adv));
      lsum += myc;
    }
    const int nt = min(64, deg - t0);
    const int ntp = (nt + 3) & ~3;
    for (int e = sub; e < ntp; e += 4) {
      float cf = __shfl(myc, e, 64);
      int s = __shfl(mys, e, 64);
      ushort4 hv = *(const ushort4*)&h2[(size_t)s * F2 + q * 4];
      acc[0] += cf * bf2f(hv.x);
      acc[1] += cf * bf2f(hv.y);
      acc[2] += cf * bf2f(hv.z);
      acc[3] += cf * bf2f(hv.w);
    }
  }
  #pragma unroll
  for (int off = 32; off > 0; off >>= 1) lsum += __shfl_xor(lsum, off, 64);
  const float rden = 1.f / lsum;

  #pragma unroll
  for (int j = 0; j < 4; ++j) {
    acc[j] += __shfl_xor(acc[j], 16, 64);
    acc[j] += __shfl_xor(acc[j], 32, 64);
  }
  float vx = __shfl(acc[0], lane >> 2, 64);
  float vy = __shfl(acc[1], lane >> 2, 64);
  float vz = __shfl(acc[2], lane >> 2, 64);
  float vw = __shfl(acc[3], lane >> 2, 64);
  int c3 = lane & 3;
  float v = (c3 == 0) ? vx : (c3 == 1) ? vy : (c3 == 2) ? vz : vw;
  v = v * rden + b[lane];
  float m = v;
  #pragma unroll
  for (int off = 32; off > 0; off >>= 1) m = fmaxf(m, __shfl_xor(m, off, 64));
  float ex = __expf(v - m);
  float ss = ex;
  #pragma unroll
  for (int off = 32; off > 0; off >>= 1) ss += __shfl_xor(ss, off, 64);
  out[(size_t)d * F2 + lane] = v - m - __logf(ss);
}

// ------------------------------- launch -------------------------------------
extern "C" void kernel_launch(void* const* d_in, const int* in_sizes, int n_in,
                              void* d_out, int out_size, void* d_ws,
                              size_t ws_size, hipStream_t stream) {
  const float* x        = (const float*)d_in[0];
  const int*   ei       = (const int*)d_in[1];
  const float* W1       = (const float*)d_in[2];
  const float* att_src1 = (const float*)d_in[3];
  const float* att_dst1 = (const float*)d_in[4];
  const float* b1       = (const float*)d_in[5];
  const float* W2       = (const float*)d_in[6];
  const float* att_src2 = (const float*)d_in[7];
  const float* att_dst2 = (const float*)d_in[8];
  const float* b2       = (const float*)d_in[9];

  const int N = in_sizes[0] / 128;
  const int E0 = in_sizes[1] / 2;
  const int Etot = E0 + N;
  const int nb1024 = (N + 1023) / 1024;

  char* w = (char*)d_ws;
  size_t off = 0;
  auto alloc = [&](size_t bytes) {
    char* p = w + off;
    off += (bytes + 255) & ~(size_t)255;
    return p;
  };
  uchar_t*  h1        = (uchar_t*) alloc((size_t)N * F1 * 1);
  ushort_t* h1out     = (ushort_t*)alloc((size_t)N * F1 * 2);
  ushort_t* h2b       = (ushort_t*)alloc((size_t)N * F2 * 2);
  int*      csr_src   = (int*)     alloc((size_t)Etot * 4);
  int*      row_start = (int*)     alloc((size_t)(N + 1) * 4);
  int*      cc        = (int*)     alloc(((size_t)2 * N + nb1024) * 4);
  int*      counts    = cc;
  int*      cursor    = cc + N;
  int*      btot      = cc + 2 * N;
  float*    a_src1    = (float*)   alloc((size_t)N * HEADS1 * 4);
  float*    a_dst1    = (float*)   alloc((size_t)N * HEADS1 * 4);
  float*    a_src2    = (float*)   alloc((size_t)N * 4);
  float*    a_dst2    = (float*)   alloc((size_t)N * 4);
  ushort_t* W1ext     = (ushort_t*)alloc(320 * 128 * 2);
  ushort_t* W2t       = (ushort_t*)alloc(256 * 64 * 2);
  float*    w_s2      = (float*)   alloc(256 * 4);
  float*    w_d2      = (float*)   alloc(256 * 4);

  hipMemsetAsync(cc, 0, ((size_t)2 * N + nb1024) * 4, stream);

  dim3 blk(256);
  const int eb = (Etot + 255) / 256;
  const int gy = (N + 63) / 64;
  const int GB1 = 5 * gy;

  kernelA<<<225 + eb, blk, 0, stream>>>(W1, W2, att_src1, att_dst1, att_src2,
                                        att_dst2, W1ext, W2t, w_s2, w_d2,
                                        ei, E0, Etot, counts);
  scan_fused<<<nb1024, blk, 0, stream>>>(counts, row_start, btot, N);

  kernelB<<<GB1 + eb, blk, 0, stream>>>(
      x, W1ext, h1, N, ei, E0, Etot, row_start, cursor, csr_src,
      a_src1, a_dst1, GB1);

  gather1<<<(N + 3) / 4, blk, 0, stream>>>(csr_src, row_start, a_src1, a_dst1,
                                           h1, b1, w_s2, w_d2, h1out, a_src2,
                                           a_dst2, N);

  gemm_bf16<<<dim3(F2 / 64, gy), blk, 0, stream>>>(h1out, W2t, h2b, N, F2, F1);
  gather2<<<(N + 3) / 4, blk, 0, stream>>>(csr_src, row_start, a_src2, a_dst2,
                                           h2b, b2, (float*)d_out, N);
}

// Round 22
// 169.874 us; speedup vs baseline: 1.3740x; 1.1502x over previous
//
#include <hip/hip_runtime.h>
#include <hip/hip_bf16.h>
#include <hip/hip_fp8.h>
#include <cmath>

// ---------------------------------------------------------------------------
// GAT 2-layer forward. R22: fill_csr's atomic eliminated — deg_count's
// atomicAdd return value is saved as eslot[e] in kernelA; kernelB's fill
// becomes a pure scatter (row_start[d] + eslot[e]). cursor buffer deleted.
// Everything else identical to R21.
// ---------------------------------------------------------------------------

#define HEADS1 8
#define F1 256
#define F2 64
#define NEG_SLOPE 0.2f

typedef unsigned int uint;
typedef unsigned short ushort_t;
typedef unsigned char uchar_t;
typedef __attribute__((ext_vector_type(8))) short bf16x8;
typedef __attribute__((ext_vector_type(4))) float f32x4;
typedef __attribute__((ext_vector_type(2))) float f32x2;

__device__ __forceinline__ float lrelu(float x) {
  return x >= 0.f ? x : NEG_SLOPE * x;
}
__device__ __forceinline__ ushort_t f2bf(float f) {
  uint u = __float_as_uint(f);
  return (ushort_t)((u + 0x7FFFu + ((u >> 16) & 1u)) >> 16);
}
__device__ __forceinline__ float bf2f(ushort_t u) {
  return __uint_as_float(((uint)u) << 16);
}
__device__ __forceinline__ uint pack2(float a, float b) {
  return (uint)f2bf(a) | ((uint)f2bf(b) << 16);
}
__device__ __forceinline__ uchar_t f2fp8(float f) {
  __hip_fp8_e4m3 t(f);
  return (uchar_t)t.__x;
}
__device__ __forceinline__ float fp82f(uchar_t u) {
  __hip_fp8_e4m3 t;
  t.__x = (__hip_fp8_storage_t)u;
  return (float)t;
}
__device__ __forceinline__ f32x4 fp8x4_decode(uint hv) {
#if __has_builtin(__builtin_amdgcn_cvt_pk_f32_fp8)
  f32x2 lo = __builtin_amdgcn_cvt_pk_f32_fp8((int)hv, false);
  f32x2 hi = __builtin_amdgcn_cvt_pk_f32_fp8((int)hv, true);
  return (f32x4){lo.x, lo.y, hi.x, hi.y};
#else
  return (f32x4){fp82f((uchar_t)(hv & 0xff)),
                 fp82f((uchar_t)((hv >> 8) & 0xff)),
                 fp82f((uchar_t)((hv >> 16) & 0xff)),
                 fp82f((uchar_t)(hv >> 24))};
#endif
}

// --- kernel A: W1ext + W2t + w_s2/w_d2 + deg_count (saves slot) -------------
__global__ __launch_bounds__(256) void kernelA(
    const float* __restrict__ W1, const float* __restrict__ W2,
    const float* __restrict__ att_src1, const float* __restrict__ att_dst1,
    const float* __restrict__ att_src2, const float* __restrict__ att_dst2,
    ushort_t* __restrict__ W1ext, ushort_t* __restrict__ W2t,
    float* __restrict__ w_s2, float* __restrict__ w_d2,
    const int* __restrict__ ei, int E0, int Etot, int* __restrict__ counts,
    int* __restrict__ eslot) {
  const int bid = blockIdx.x;
  const int tid = threadIdx.x;
  if (bid < 128) {
    int idx = bid * 256 + tid;
    int r = idx >> 8, c = idx & 255;
    W1ext[(size_t)c * 128 + r] = f2bf(W1[idx]);
  } else if (bid < 192) {
    int idx = (bid - 128) * 256 + tid;
    int r = idx >> 6, c = idx & 63;
    W2t[(size_t)c * 256 + r] = f2bf(W2[idx]);
  } else if (bid < 200) {
    int idx = (bid - 192) * 256 + tid;   // 0..2047
    int r16 = idx >> 7;                  // 0..15
    int k = idx & 127;
    const float* att = (r16 < 8) ? att_src1 : att_dst1;
    int h = r16 & 7;
    float v = 0.f;
    #pragma unroll
    for (int c = 0; c < 32; ++c)
      v += W1[(size_t)k * 256 + h * 32 + c] * att[h * 32 + c];
    W1ext[(size_t)(256 + r16) * 128 + k] = f2bf(v);
  } else if (bid < 224) {
    int idx = (bid - 200) * 256 + tid;   // 0..6143
    W1ext[(size_t)272 * 128 + idx] = 0;
  } else if (bid < 225) {
    int k = tid;
    float as = 0.f, ad = 0.f;
    #pragma unroll
    for (int c = 0; c < 64; ++c) {
      float wv = W2[(size_t)k * 64 + c];
      as += wv * att_src2[c];
      ad += wv * att_dst2[c];
    }
    w_s2[k] = as;
    w_d2[k] = ad;
  } else {
    int e = (bid - 225) * 256 + tid;
    if (e >= Etot) return;
    int d = (e < E0) ? ei[E0 + e] : (e - E0);
    eslot[e] = atomicAdd(&counts[d], 1);
  }
}

// ------------- fused exclusive scan: decoupled lookback, 1 kernel -----------
__global__ __launch_bounds__(256) void scan_fused(
    const int* __restrict__ counts, int* __restrict__ row_start,
    int* __restrict__ btot, int n) {
  __shared__ int wsum[4];
  __shared__ int s_prev;
  const int tid = threadIdx.x;
  const int lane = tid & 63;
  const int wid = tid >> 6;
  const int base = blockIdx.x * 1024 + tid * 4;
  int c[4], inc[4];
  #pragma unroll
  for (int j = 0; j < 4; ++j)
    c[j] = (base + j < n) ? counts[base + j] : 0;
  inc[0] = c[0];
  #pragma unroll
  for (int j = 1; j < 4; ++j) inc[j] = inc[j - 1] + c[j];
  int tsum = inc[3];
  int wincl = tsum;
  #pragma unroll
  for (int off = 1; off < 64; off <<= 1) {
    int v = __shfl_up(wincl, off, 64);
    if (lane >= off) wincl += v;
  }
  if (lane == 63) wsum[wid] = wincl;
  __syncthreads();
  int woff = 0;
  #pragma unroll
  for (int j = 0; j < 4; ++j)
    if (j < wid) woff += wsum[j];

  if (tid == 255) atomicExch(&btot[blockIdx.x], woff + wincl);

  if (wid == 0) {
    int run = 0;
    if (lane < blockIdx.x) {
      int v;
      do {
        v = atomicAdd(&btot[lane], 0);
      } while (v == 0);
      run = v;
    }
    #pragma unroll
    for (int off = 32; off > 0; off >>= 1) run += __shfl_xor(run, off, 64);
    if (lane == 0) s_prev = run;
  }
  __syncthreads();

  int prefix = s_prev + woff + (wincl - tsum);
  #pragma unroll
  for (int j = 0; j < 4; ++j)
    if (base + j < n) row_start[base + j + 1] = prefix + inc[j];
  if (blockIdx.x == 0 && tid == 0) row_start[0] = 0;
}

// ------- kernel B: widened gemm1 + atomic-free fill_csr ---------------------
__global__ __launch_bounds__(256) void kernelB(
    const float* __restrict__ x, const ushort_t* __restrict__ W1ext,
    uchar_t* __restrict__ h1, int M,
    const int* __restrict__ ei, int E0, int Etot,
    const int* __restrict__ row_start, const int* __restrict__ eslot,
    int* __restrict__ csr_src,
    float* __restrict__ a_src, float* __restrict__ a_dst,
    int GB1) {
  __shared__ char smem[10240];
  const int bid = blockIdx.x;
  const int tid = threadIdx.x;

  if (bid < GB1) {
    ushort_t* As = (ushort_t*)smem;
    ushort_t* Bs = As + 64 * 40;
    const int lane = tid & 63;
    const int wave = tid >> 6;
    const int wr = wave >> 1, wc = wave & 1;
    const int ct = bid % 5;
    const int row0 = (bid / 5) * 64, col0 = ct * 64;
    const int sr = tid >> 2;
    const int sk = (tid & 3) * 8;
    const int l15 = lane & 15;
    const int lk8 = (lane >> 4) * 8;
    const int K = 128;

    f32x4 acc[2][2];
    #pragma unroll
    for (int i = 0; i < 2; ++i)
      #pragma unroll
      for (int j = 0; j < 2; ++j) acc[i][j] = (f32x4){0.f, 0.f, 0.f, 0.f};

    for (int k0 = 0; k0 < K; k0 += 32) {
      const int gr = row0 + sr;
      float4 f0 = {0.f, 0.f, 0.f, 0.f}, f1 = {0.f, 0.f, 0.f, 0.f};
      if (gr < M) {
        f0 = *(const float4*)&x[(size_t)gr * K + k0 + sk];
        f1 = *(const float4*)&x[(size_t)gr * K + k0 + sk + 4];
      }
      uint4 av;
      av.x = pack2(f0.x, f0.y);
      av.y = pack2(f0.z, f0.w);
      av.z = pack2(f1.x, f1.y);
      av.w = pack2(f1.z, f1.w);
      *(uint4*)&As[sr * 40 + sk] = av;
      uint4 bv = *(const uint4*)&W1ext[(size_t)(col0 + sr) * K + k0 + sk];
      *(uint4*)&Bs[sr * 40 + sk] = bv;
      __syncthreads();

      bf16x8 af[2], bfr[2];
      #pragma unroll
      for (int mi = 0; mi < 2; ++mi)
        af[mi] = *(const bf16x8*)&As[(wr * 32 + mi * 16 + l15) * 40 + lk8];
      #pragma unroll
      for (int ni = 0; ni < 2; ++ni)
        bfr[ni] = *(const bf16x8*)&Bs[(wc * 32 + ni * 16 + l15) * 40 + lk8];
      #pragma unroll
      for (int mi = 0; mi < 2; ++mi)
        #pragma unroll
        for (int ni = 0; ni < 2; ++ni)
          acc[mi][ni] = __builtin_amdgcn_mfma_f32_16x16x32_bf16(
              af[mi], bfr[ni], acc[mi][ni], 0, 0, 0);
      __syncthreads();
    }

    #pragma unroll
    for (int mi = 0; mi < 2; ++mi) {
      #pragma unroll
      for (int ni = 0; ni < 2; ++ni) {
        #pragma unroll
        for (int r = 0; r < 4; ++r) {
          int grow = row0 + wr * 32 + mi * 16 + (lane >> 4) * 4 + r;
          int gcol = col0 + wc * 32 + ni * 16 + l15;
          if (grow >= M) continue;
          float v = acc[mi][ni][r];
          if (gcol < 256) {
            h1[(size_t)grow * F1 + gcol] = f2fp8(v);
          } else if (gcol < 264) {
            a_src[(size_t)grow * 8 + (gcol - 256)] = v;
          } else if (gcol < 272) {
            a_dst[(size_t)grow * 8 + (gcol - 264)] = v;
          }
        }
      }
    }
  } else {
    int e = (bid - GB1) * 256 + tid;
    if (e >= Etot) return;
    int s, d;
    if (e < E0) { s = ei[e]; d = ei[E0 + e]; } else { s = d = e - E0; }
    csr_src[row_start[d] + eslot[e]] = s;   // atomic-free scatter
  }
}

// -------------------------- MFMA GEMM (layer 2) -----------------------------
__global__ __launch_bounds__(256) void gemm_bf16(
    const ushort_t* __restrict__ Ab, const ushort_t* __restrict__ Bt,
    ushort_t* __restrict__ Cb, int M, int N, int K) {
  __shared__ ushort_t As[64 * 40];
  __shared__ ushort_t Bs[64 * 40];
  const int tid = threadIdx.x;
  const int lane = tid & 63;
  const int wave = tid >> 6;
  const int wr = wave >> 1, wc = wave & 1;
  const int row0 = blockIdx.y * 64, col0 = blockIdx.x * 64;
  const int sr = tid >> 2;
  const int sk = (tid & 3) * 8;
  const int l15 = lane & 15;
  const int lk8 = (lane >> 4) * 8;

  f32x4 acc[2][2];
  #pragma unroll
  for (int i = 0; i < 2; ++i)
    #pragma unroll
    for (int j = 0; j < 2; ++j) acc[i][j] = (f32x4){0.f, 0.f, 0.f, 0.f};

  for (int k0 = 0; k0 < K; k0 += 32) {
    const int gr = row0 + sr;
    uint4 av = {0u, 0u, 0u, 0u};
    if (gr < M) av = *(const uint4*)&Ab[(size_t)gr * K + k0 + sk];
    *(uint4*)&As[sr * 40 + sk] = av;
    uint4 bv = *(const uint4*)&Bt[(size_t)(col0 + sr) * K + k0 + sk];
    *(uint4*)&Bs[sr * 40 + sk] = bv;
    __syncthreads();

    bf16x8 af[2], bfr[2];
    #pragma unroll
    for (int mi = 0; mi < 2; ++mi)
      af[mi] = *(const bf16x8*)&As[(wr * 32 + mi * 16 + l15) * 40 + lk8];
    #pragma unroll
    for (int ni = 0; ni < 2; ++ni)
      bfr[ni] = *(const bf16x8*)&Bs[(wc * 32 + ni * 16 + l15) * 40 + lk8];
    #pragma unroll
    for (int mi = 0; mi < 2; ++mi)
      #pragma unroll
      for (int ni = 0; ni < 2; ++ni)
        acc[mi][ni] = __builtin_amdgcn_mfma_f32_16x16x32_bf16(
            af[mi], bfr[ni], acc[mi][ni], 0, 0, 0);
    __syncthreads();
  }

  #pragma unroll
  for (int mi = 0; mi < 2; ++mi) {
    #pragma unroll
    for (int ni = 0; ni < 2; ++ni) {
      #pragma unroll
      for (int r = 0; r < 4; ++r) {
        int grow = row0 + wr * 32 + mi * 16 + (lane >> 4) * 4 + r;
        int gcol = col0 + wc * 32 + ni * 16 + l15;
        if (grow < M) Cb[(size_t)grow * N + gcol] = f2bf(acc[mi][ni][r]);
      }
    }
  }
}

// ------- gather layer 1: wave-per-node, FIXED 8-iter consumer (8x MLP) ------
__global__ __launch_bounds__(256) void gather1(
    const int* __restrict__ csr_src, const int* __restrict__ row_start,
    const float* __restrict__ a_src, const float* __restrict__ a_dst,
    const uchar_t* __restrict__ h1, const float* __restrict__ b,
    const float* __restrict__ ws2, const float* __restrict__ wd2,
    ushort_t* __restrict__ out, float* __restrict__ a_src2,
    float* __restrict__ a_dst2, int n) {
  const int d = blockIdx.x * 4 + (threadIdx.x >> 6);
  const int lane = threadIdx.x & 63;
  if (d >= n) return;
  const int rs = row_start[d];
  const int deg = row_start[d + 1] - rs;
  const int pe = lane >> 3;
  const int ph = lane & 7;
  const int hsel = lane >> 3;
  const float adv = a_dst[d * 8 + ph];

  float dpart = 0.f;
  f32x4 acc = {0.f, 0.f, 0.f, 0.f};

  for (int t0 = 0; t0 < deg; t0 += 8) {
    const int myi = t0 + pe;
    int mys = 0;
    float myc = 0.f;
    if (myi < deg) {
      mys = csr_src[rs + myi];
      myc = __expf(lrelu(a_src[mys * 8 + ph] + adv));
      dpart += myc;
    }
    #pragma unroll
    for (int jj = 0; jj < 8; ++jj) {
      float cf = __shfl(myc, jj * 8 + hsel, 64);
      int s = __shfl(mys, jj * 8, 64);
      uint hv = *(const uint*)&h1[(size_t)s * F1 + lane * 4];
      f32x4 hd = fp8x4_decode(hv);
      acc[0] += cf * hd[0];
      acc[1] += cf * hd[1];
      acc[2] += cf * hd[2];
      acc[3] += cf * hd[3];
    }
  }

  dpart += __shfl_xor(dpart, 8, 64);
  dpart += __shfl_xor(dpart, 16, 64);
  dpart += __shfl_xor(dpart, 32, 64);
  const float rden = 1.f / __shfl(dpart, hsel, 64);

  const int ch = lane * 4;
  ushort4 ob;
  float ps = 0.f, pd = 0.f;
  #pragma unroll
  for (int j = 0; j < 4; ++j) {
    float v = fmaxf(acc[j] * rden + b[ch + j], 0.f);
    ushort_t bv = f2bf(v);
    ((ushort_t*)&ob)[j] = bv;
    float r = bf2f(bv);
    ps += r * ws2[ch + j];
    pd += r * wd2[ch + j];
  }
  *(ushort4*)&out[(size_t)d * F1 + ch] = ob;
  #pragma unroll
  for (int off = 32; off > 0; off >>= 1) {
    ps += __shfl_xor(ps, off, 64);
    pd += __shfl_xor(pd, off, 64);
  }
  if (lane == 0) {
    a_src2[d] = ps;
    a_dst2[d] = pd;
  }
}

// ------ gather layer 2 + log_softmax: 4-edge-parallel, UNIFORM trip count ---
__global__ __launch_bounds__(256) void gather2(
    const int* __restrict__ csr_src, const int* __restrict__ row_start,
    const float* __restrict__ a_src, const float* __restrict__ a_dst,
    const ushort_t* __restrict__ h2, const float* __restrict__ b,
    float* __restrict__ out, int n) {
  const int d = blockIdx.x * 4 + (threadIdx.x >> 6);
  const int lane = threadIdx.x & 63;
  if (d >= n) return;
  const int rs = row_start[d];
  const int deg = row_start[d + 1] - rs;
  const float adv = a_dst[d];

  const int sub = lane >> 4;
  const int q = lane & 15;
  float lsum = 0.f;
  f32x4 acc = {0.f, 0.f, 0.f, 0.f};
  for (int t0 = 0; t0 < deg; t0 += 64) {
    int myi = t0 + lane;
    int mys = 0;
    float myc = 0.f;
    if (myi < deg) {
      mys = csr_src[rs + myi];
      myc = __expf(lrelu(a_src[mys] + adv));
      lsum += myc;
    }
    const int nt = min(64, deg - t0);
    const int ntp = (nt + 3) & ~3;
    for (int e = sub; e < ntp; e += 4) {
      float cf = __shfl(myc, e, 64);
      int s = __shfl(mys, e, 64);
      ushort4 hv = *(const ushort4*)&h2[(size_t)s * F2 + q * 4];
      acc[0] += cf * bf2f(hv.x);
      acc[1] += cf * bf2f(hv.y);
      acc[2] += cf * bf2f(hv.z);
      acc[3] += cf * bf2f(hv.w);
    }
  }
  #pragma unroll
  for (int off = 32; off > 0; off >>= 1) lsum += __shfl_xor(lsum, off, 64);
  const float rden = 1.f / lsum;

  #pragma unroll
  for (int j = 0; j < 4; ++j) {
    acc[j] += __shfl_xor(acc[j], 16, 64);
    acc[j] += __shfl_xor(acc[j], 32, 64);
  }
  float vx = __shfl(acc[0], lane >> 2, 64);
  float vy = __shfl(acc[1], lane >> 2, 64);
  float vz = __shfl(acc[2], lane >> 2, 64);
  float vw = __shfl(acc[3], lane >> 2, 64);
  int c3 = lane & 3;
  float v = (c3 == 0) ? vx : (c3 == 1) ? vy : (c3 == 2) ? vz : vw;
  v = v * rden + b[lane];
  float m = v;
  #pragma unroll
  for (int off = 32; off > 0; off >>= 1) m = fmaxf(m, __shfl_xor(m, off, 64));
  float ex = __expf(v - m);
  float ss = ex;
  #pragma unroll
  for (int off = 32; off > 0; off >>= 1) ss += __shfl_xor(ss, off, 64);
  out[(size_t)d * F2 + lane] = v - m - __logf(ss);
}

// ------------------------------- launch -------------------------------------
extern "C" void kernel_launch(void* const* d_in, const int* in_sizes, int n_in,
                              void* d_out, int out_size, void* d_ws,
                              size_t ws_size, hipStream_t stream) {
  const float* x        = (const float*)d_in[0];
  const int*   ei       = (const int*)d_in[1];
  const float* W1       = (const float*)d_in[2];
  const float* att_src1 = (const float*)d_in[3];
  const float* att_dst1 = (const float*)d_in[4];
  const float* b1       = (const float*)d_in[5];
  const float* W2       = (const float*)d_in[6];
  const float* att_src2 = (const float*)d_in[7];
  const float* att_dst2 = (const float*)d_in[8];
  const float* b2       = (const float*)d_in[9];

  const int N = in_sizes[0] / 128;
  const int E0 = in_sizes[1] / 2;
  const int Etot = E0 + N;
  const int nb1024 = (N + 1023) / 1024;

  char* w = (char*)d_ws;
  size_t off = 0;
  auto alloc = [&](size_t bytes) {
    char* p = w + off;
    off += (bytes + 255) & ~(size_t)255;
    return p;
  };
  uchar_t*  h1        = (uchar_t*) alloc((size_t)N * F1 * 1);
  ushort_t* h1out     = (ushort_t*)alloc((size_t)N * F1 * 2);
  ushort_t* h2b       = (ushort_t*)alloc((size_t)N * F2 * 2);
  int*      csr_src   = (int*)     alloc((size_t)Etot * 4);
  int*      eslot     = (int*)     alloc((size_t)Etot * 4);
  int*      row_start = (int*)     alloc((size_t)(N + 1) * 4);
  int*      cc        = (int*)     alloc(((size_t)N + nb1024) * 4);
  int*      counts    = cc;
  int*      btot      = cc + N;
  float*    a_src1    = (float*)   alloc((size_t)N * HEADS1 * 4);
  float*    a_dst1    = (float*)   alloc((size_t)N * HEADS1 * 4);
  float*    a_src2    = (float*)   alloc((size_t)N * 4);
  float*    a_dst2    = (float*)   alloc((size_t)N * 4);
  ushort_t* W1ext     = (ushort_t*)alloc(320 * 128 * 2);
  ushort_t* W2t       = (ushort_t*)alloc(256 * 64 * 2);
  float*    w_s2      = (float*)   alloc(256 * 4);
  float*    w_d2      = (float*)   alloc(256 * 4);

  hipMemsetAsync(cc, 0, ((size_t)N + nb1024) * 4, stream);

  dim3 blk(256);
  const int eb = (Etot + 255) / 256;
  const int gy = (N + 63) / 64;
  const int GB1 = 5 * gy;

  kernelA<<<225 + eb, blk, 0, stream>>>(W1, W2, att_src1, att_dst1, att_src2,
                                        att_dst2, W1ext, W2t, w_s2, w_d2,
                                        ei, E0, Etot, counts, eslot);
  scan_fused<<<nb1024, blk, 0, stream>>>(counts, row_start, btot, N);

  kernelB<<<GB1 + eb, blk, 0, stream>>>(
      x, W1ext, h1, N, ei, E0, Etot, row_start, eslot, csr_src,
      a_src1, a_dst1, GB1);

  gather1<<<(N + 3) / 4, blk, 0, stream>>>(csr_src, row_start, a_src1, a_dst1,
                                           h1, b1, w_s2, w_d2, h1out, a_src2,
                                           a_dst2, N);

  gemm_bf16<<<dim3(F2 / 64, gy), blk, 0, stream>>>(h1out, W2t, h2b, N, F2, F1);
  gather2<<<(N + 3) / 4, blk, 0, stream>>>(csr_src, row_start, a_src2, a_dst2,
                                           h2b, b2, (float*)d_out, N);
}

// Round 23
// 164.704 us; speedup vs baseline: 1.4171x; 1.0314x over previous
//
#include <hip/hip_runtime.h>
#include <hip/hip_bf16.h>
#include <hip/hip_fp8.h>
#include <cmath>

// ---------------------------------------------------------------------------
// GAT 2-layer forward. R23: kernelB gemm = full 64x320 row-stripe per block
// (As staged once; h1 row buffered in LDS and flushed as full 256B lines,
// killing the 4x partial-line write amplification). Everything else = R22.
// ---------------------------------------------------------------------------

#define HEADS1 8
#define F1 256
#define F2 64
#define NEG_SLOPE 0.2f
#define KP 136   // LDS K-pitch (elems) for As/Bs
#define HP 272   // LDS byte-pitch for h1 row buffer

typedef unsigned int uint;
typedef unsigned short ushort_t;
typedef unsigned char uchar_t;
typedef __attribute__((ext_vector_type(8))) short bf16x8;
typedef __attribute__((ext_vector_type(4))) float f32x4;
typedef __attribute__((ext_vector_type(2))) float f32x2;

__device__ __forceinline__ float lrelu(float x) {
  return x >= 0.f ? x : NEG_SLOPE * x;
}
__device__ __forceinline__ ushort_t f2bf(float f) {
  uint u = __float_as_uint(f);
  return (ushort_t)((u + 0x7FFFu + ((u >> 16) & 1u)) >> 16);
}
__device__ __forceinline__ float bf2f(ushort_t u) {
  return __uint_as_float(((uint)u) << 16);
}
__device__ __forceinline__ uint pack2(float a, float b) {
  return (uint)f2bf(a) | ((uint)f2bf(b) << 16);
}
__device__ __forceinline__ uchar_t f2fp8(float f) {
  __hip_fp8_e4m3 t(f);
  return (uchar_t)t.__x;
}
__device__ __forceinline__ float fp82f(uchar_t u) {
  __hip_fp8_e4m3 t;
  t.__x = (__hip_fp8_storage_t)u;
  return (float)t;
}
__device__ __forceinline__ f32x4 fp8x4_decode(uint hv) {
#if __has_builtin(__builtin_amdgcn_cvt_pk_f32_fp8)
  f32x2 lo = __builtin_amdgcn_cvt_pk_f32_fp8((int)hv, false);
  f32x2 hi = __builtin_amdgcn_cvt_pk_f32_fp8((int)hv, true);
  return (f32x4){lo.x, lo.y, hi.x, hi.y};
#else
  return (f32x4){fp82f((uchar_t)(hv & 0xff)),
                 fp82f((uchar_t)((hv >> 8) & 0xff)),
                 fp82f((uchar_t)((hv >> 16) & 0xff)),
                 fp82f((uchar_t)(hv >> 24))};
#endif
}

// --- kernel A: W1ext + W2t + w_s2/w_d2 + deg_count (saves slot) -------------
__global__ __launch_bounds__(256) void kernelA(
    const float* __restrict__ W1, const float* __restrict__ W2,
    const float* __restrict__ att_src1, const float* __restrict__ att_dst1,
    const float* __restrict__ att_src2, const float* __restrict__ att_dst2,
    ushort_t* __restrict__ W1ext, ushort_t* __restrict__ W2t,
    float* __restrict__ w_s2, float* __restrict__ w_d2,
    const int* __restrict__ ei, int E0, int Etot, int* __restrict__ counts,
    int* __restrict__ eslot) {
  const int bid = blockIdx.x;
  const int tid = threadIdx.x;
  if (bid < 128) {
    int idx = bid * 256 + tid;
    int r = idx >> 8, c = idx & 255;
    W1ext[(size_t)c * 128 + r] = f2bf(W1[idx]);
  } else if (bid < 192) {
    int idx = (bid - 128) * 256 + tid;
    int r = idx >> 6, c = idx & 63;
    W2t[(size_t)c * 256 + r] = f2bf(W2[idx]);
  } else if (bid < 200) {
    int idx = (bid - 192) * 256 + tid;   // 0..2047
    int r16 = idx >> 7;                  // 0..15
    int k = idx & 127;
    const float* att = (r16 < 8) ? att_src1 : att_dst1;
    int h = r16 & 7;
    float v = 0.f;
    #pragma unroll
    for (int c = 0; c < 32; ++c)
      v += W1[(size_t)k * 256 + h * 32 + c] * att[h * 32 + c];
    W1ext[(size_t)(256 + r16) * 128 + k] = f2bf(v);
  } else if (bid < 224) {
    int idx = (bid - 200) * 256 + tid;   // 0..6143
    W1ext[(size_t)272 * 128 + idx] = 0;
  } else if (bid < 225) {
    int k = tid;
    float as = 0.f, ad = 0.f;
    #pragma unroll
    for (int c = 0; c < 64; ++c) {
      float wv = W2[(size_t)k * 64 + c];
      as += wv * att_src2[c];
      ad += wv * att_dst2[c];
    }
    w_s2[k] = as;
    w_d2[k] = ad;
  } else {
    int e = (bid - 225) * 256 + tid;
    if (e >= Etot) return;
    int d = (e < E0) ? ei[E0 + e] : (e - E0);
    eslot[e] = atomicAdd(&counts[d], 1);
  }
}

// ------------- fused exclusive scan: decoupled lookback, 1 kernel -----------
__global__ __launch_bounds__(256) void scan_fused(
    const int* __restrict__ counts, int* __restrict__ row_start,
    int* __restrict__ btot, int n) {
  __shared__ int wsum[4];
  __shared__ int s_prev;
  const int tid = threadIdx.x;
  const int lane = tid & 63;
  const int wid = tid >> 6;
  const int base = blockIdx.x * 1024 + tid * 4;
  int c[4], inc[4];
  #pragma unroll
  for (int j = 0; j < 4; ++j)
    c[j] = (base + j < n) ? counts[base + j] : 0;
  inc[0] = c[0];
  #pragma unroll
  for (int j = 1; j < 4; ++j) inc[j] = inc[j - 1] + c[j];
  int tsum = inc[3];
  int wincl = tsum;
  #pragma unroll
  for (int off = 1; off < 64; off <<= 1) {
    int v = __shfl_up(wincl, off, 64);
    if (lane >= off) wincl += v;
  }
  if (lane == 63) wsum[wid] = wincl;
  __syncthreads();
  int woff = 0;
  #pragma unroll
  for (int j = 0; j < 4; ++j)
    if (j < wid) woff += wsum[j];

  if (tid == 255) atomicExch(&btot[blockIdx.x], woff + wincl);

  if (wid == 0) {
    int run = 0;
    if (lane < blockIdx.x) {
      int v;
      do {
        v = atomicAdd(&btot[lane], 0);
      } while (v == 0);
      run = v;
    }
    #pragma unroll
    for (int off = 32; off > 0; off >>= 1) run += __shfl_xor(run, off, 64);
    if (lane == 0) s_prev = run;
  }
  __syncthreads();

  int prefix = s_prev + woff + (wincl - tsum);
  #pragma unroll
  for (int j = 0; j < 4; ++j)
    if (base + j < n) row_start[base + j + 1] = prefix + inc[j];
  if (blockIdx.x == 0 && tid == 0) row_start[0] = 0;
}

// ------- kernel B: row-stripe gemm1 (64x320/block) + atomic-free fill -------
__global__ __launch_bounds__(256) void kernelB(
    const float* __restrict__ x, const ushort_t* __restrict__ W1ext,
    uchar_t* __restrict__ h1, int M,
    const int* __restrict__ ei, int E0, int Etot,
    const int* __restrict__ row_start, const int* __restrict__ eslot,
    int* __restrict__ csr_src,
    float* __restrict__ a_src, float* __restrict__ a_dst,
    int GB1) {
  __shared__ ushort_t AsF[64 * KP];     // 17408 B
  __shared__ ushort_t BsF[64 * KP];     // 17408 B
  __shared__ uchar_t  h1row[64 * HP];   // 17408 B
  const int bid = blockIdx.x;
  const int tid = threadIdx.x;

  if (bid < GB1) {
    const int lane = tid & 63;
    const int wave = tid >> 6;
    const int wr = wave >> 1, wc = wave & 1;
    const int row0 = bid * 64;
    const int sr = tid >> 2;
    const int sk = (tid & 3) * 8;
    const int l15 = lane & 15;
    const int lk8 = (lane >> 4) * 8;
    const int K = 128;

    // stage As once: 4 passes of 64 rows x 32 k
    #pragma unroll
    for (int k0 = 0; k0 < K; k0 += 32) {
      const int gr = row0 + sr;
      float4 f0 = {0.f, 0.f, 0.f, 0.f}, f1 = {0.f, 0.f, 0.f, 0.f};
      if (gr < M) {
        f0 = *(const float4*)&x[(size_t)gr * K + k0 + sk];
        f1 = *(const float4*)&x[(size_t)gr * K + k0 + sk + 4];
      }
      uint4 av;
      av.x = pack2(f0.x, f0.y);
      av.y = pack2(f0.z, f0.w);
      av.z = pack2(f1.x, f1.y);
      av.w = pack2(f1.z, f1.w);
      *(uint4*)&AsF[sr * KP + k0 + sk] = av;
    }

    for (int ct = 0; ct < 5; ++ct) {
      const int col0 = ct * 64;
      __syncthreads();   // As ready (ct=0) / prev MFMA done reading Bs
      #pragma unroll
      for (int k0 = 0; k0 < K; k0 += 32) {
        uint4 bv = *(const uint4*)&W1ext[(size_t)(col0 + sr) * K + k0 + sk];
        *(uint4*)&BsF[sr * KP + k0 + sk] = bv;
      }
      __syncthreads();

      f32x4 acc[2][2];
      #pragma unroll
      for (int i = 0; i < 2; ++i)
        #pragma unroll
        for (int j = 0; j < 2; ++j) acc[i][j] = (f32x4){0.f, 0.f, 0.f, 0.f};

      #pragma unroll
      for (int k0 = 0; k0 < K; k0 += 32) {
        bf16x8 af[2], bfr[2];
        #pragma unroll
        for (int mi = 0; mi < 2; ++mi)
          af[mi] = *(const bf16x8*)&AsF[(wr * 32 + mi * 16 + l15) * KP + k0 + lk8];
        #pragma unroll
        for (int ni = 0; ni < 2; ++ni)
          bfr[ni] = *(const bf16x8*)&BsF[(wc * 32 + ni * 16 + l15) * KP + k0 + lk8];
        #pragma unroll
        for (int mi = 0; mi < 2; ++mi)
          #pragma unroll
          for (int ni = 0; ni < 2; ++ni)
            acc[mi][ni] = __builtin_amdgcn_mfma_f32_16x16x32_bf16(
                af[mi], bfr[ni], acc[mi][ni], 0, 0, 0);
      }

      // epilogue for this column tile
      if (ct < 4) {
        #pragma unroll
        for (int mi = 0; mi < 2; ++mi)
          #pragma unroll
          for (int ni = 0; ni < 2; ++ni)
            #pragma unroll
            for (int r = 0; r < 4; ++r) {
              int lrow = wr * 32 + mi * 16 + (lane >> 4) * 4 + r;
              int lcol = col0 + wc * 32 + ni * 16 + l15;
              h1row[lrow * HP + lcol] = f2fp8(acc[mi][ni][r]);
            }
      } else {
        #pragma unroll
        for (int mi = 0; mi < 2; ++mi)
          #pragma unroll
          for (int ni = 0; ni < 2; ++ni)
            #pragma unroll
            for (int r = 0; r < 4; ++r) {
              int grow = row0 + wr * 32 + mi * 16 + (lane >> 4) * 4 + r;
              int c = wc * 32 + ni * 16 + l15;   // 0..63 (=global col-256)
              if (grow >= M) continue;
              float v = acc[mi][ni][r];
              if (c < 8) a_src[(size_t)grow * 8 + c] = v;
              else if (c < 16) a_dst[(size_t)grow * 8 + (c - 8)] = v;
            }
      }
    }

    // flush h1 rows as full 256B lines
    __syncthreads();
    const int r = tid >> 2, q = tid & 3;
    const int grow = row0 + r;
    if (grow < M) {
      #pragma unroll
      for (int j = 0; j < 4; ++j) {
        uint4 v = *(uint4*)&h1row[r * HP + q * 64 + j * 16];
        *(uint4*)&h1[(size_t)grow * F1 + q * 64 + j * 16] = v;
      }
    }
  } else {
    int e = (bid - GB1) * 256 + tid;
    if (e >= Etot) return;
    int s, d;
    if (e < E0) { s = ei[e]; d = ei[E0 + e]; } else { s = d = e - E0; }
    csr_src[row_start[d] + eslot[e]] = s;
  }
}

// -------------------------- MFMA GEMM (layer 2) -----------------------------
__global__ __launch_bounds__(256) void gemm_bf16(
    const ushort_t* __restrict__ Ab, const ushort_t* __restrict__ Bt,
    ushort_t* __restrict__ Cb, int M, int N, int K) {
  __shared__ ushort_t As[64 * 40];
  __shared__ ushort_t Bs[64 * 40];
  const int tid = threadIdx.x;
  const int lane = tid & 63;
  const int wave = tid >> 6;
  const int wr = wave >> 1, wc = wave & 1;
  const int row0 = blockIdx.y * 64, col0 = blockIdx.x * 64;
  const int sr = tid >> 2;
  const int sk = (tid & 3) * 8;
  const int l15 = lane & 15;
  const int lk8 = (lane >> 4) * 8;

  f32x4 acc[2][2];
  #pragma unroll
  for (int i = 0; i < 2; ++i)
    #pragma unroll
    for (int j = 0; j < 2; ++j) acc[i][j] = (f32x4){0.f, 0.f, 0.f, 0.f};

  for (int k0 = 0; k0 < K; k0 += 32) {
    const int gr = row0 + sr;
    uint4 av = {0u, 0u, 0u, 0u};
    if (gr < M) av = *(const uint4*)&Ab[(size_t)gr * K + k0 + sk];
    *(uint4*)&As[sr * 40 + sk] = av;
    uint4 bv = *(const uint4*)&Bt[(size_t)(col0 + sr) * K + k0 + sk];
    *(uint4*)&Bs[sr * 40 + sk] = bv;
    __syncthreads();

    bf16x8 af[2], bfr[2];
    #pragma unroll
    for (int mi = 0; mi < 2; ++mi)
      af[mi] = *(const bf16x8*)&As[(wr * 32 + mi * 16 + l15) * 40 + lk8];
    #pragma unroll
    for (int ni = 0; ni < 2; ++ni)
      bfr[ni] = *(const bf16x8*)&Bs[(wc * 32 + ni * 16 + l15) * 40 + lk8];
    #pragma unroll
    for (int mi = 0; mi < 2; ++mi)
      #pragma unroll
      for (int ni = 0; ni < 2; ++ni)
        acc[mi][ni] = __builtin_amdgcn_mfma_f32_16x16x32_bf16(
            af[mi], bfr[ni], acc[mi][ni], 0, 0, 0);
    __syncthreads();
  }

  #pragma unroll
  for (int mi = 0; mi < 2; ++mi) {
    #pragma unroll
    for (int ni = 0; ni < 2; ++ni) {
      #pragma unroll
      for (int r = 0; r < 4; ++r) {
        int grow = row0 + wr * 32 + mi * 16 + (lane >> 4) * 4 + r;
        int gcol = col0 + wc * 32 + ni * 16 + l15;
        if (grow < M) Cb[(size_t)grow * N + gcol] = f2bf(acc[mi][ni][r]);
      }
    }
  }
}

// ------- gather layer 1: wave-per-node, FIXED 8-iter consumer (8x MLP) ------
__global__ __launch_bounds__(256) void gather1(
    const int* __restrict__ csr_src, const int* __restrict__ row_start,
    const float* __restrict__ a_src, const float* __restrict__ a_dst,
    const uchar_t* __restrict__ h1, const float* __restrict__ b,
    const float* __restrict__ ws2, const float* __restrict__ wd2,
    ushort_t* __restrict__ out, float* __restrict__ a_src2,
    float* __restrict__ a_dst2, int n) {
  const int d = blockIdx.x * 4 + (threadIdx.x >> 6);
  const int lane = threadIdx.x & 63;
  if (d >= n) return;
  const int rs = row_start[d];
  const int deg = row_start[d + 1] - rs;
  const int pe = lane >> 3;
  const int ph = lane & 7;
  const int hsel = lane >> 3;
  const float adv = a_dst[d * 8 + ph];

  float dpart = 0.f;
  f32x4 acc = {0.f, 0.f, 0.f, 0.f};

  for (int t0 = 0; t0 < deg; t0 += 8) {
    const int myi = t0 + pe;
    int mys = 0;
    float myc = 0.f;
    if (myi < deg) {
      mys = csr_src[rs + myi];
      myc = __expf(lrelu(a_src[mys * 8 + ph] + adv));
      dpart += myc;
    }
    #pragma unroll
    for (int jj = 0; jj < 8; ++jj) {
      float cf = __shfl(myc, jj * 8 + hsel, 64);
      int s = __shfl(mys, jj * 8, 64);
      uint hv = *(const uint*)&h1[(size_t)s * F1 + lane * 4];
      f32x4 hd = fp8x4_decode(hv);
      acc[0] += cf * hd[0];
      acc[1] += cf * hd[1];
      acc[2] += cf * hd[2];
      acc[3] += cf * hd[3];
    }
  }

  dpart += __shfl_xor(dpart, 8, 64);
  dpart += __shfl_xor(dpart, 16, 64);
  dpart += __shfl_xor(dpart, 32, 64);
  const float rden = 1.f / __shfl(dpart, hsel, 64);

  const int ch = lane * 4;
  ushort4 ob;
  float ps = 0.f, pd = 0.f;
  #pragma unroll
  for (int j = 0; j < 4; ++j) {
    float v = fmaxf(acc[j] * rden + b[ch + j], 0.f);
    ushort_t bv = f2bf(v);
    ((ushort_t*)&ob)[j] = bv;
    float r = bf2f(bv);
    ps += r * ws2[ch + j];
    pd += r * wd2[ch + j];
  }
  *(ushort4*)&out[(size_t)d * F1 + ch] = ob;
  #pragma unroll
  for (int off = 32; off > 0; off >>= 1) {
    ps += __shfl_xor(ps, off, 64);
    pd += __shfl_xor(pd, off, 64);
  }
  if (lane == 0) {
    a_src2[d] = ps;
    a_dst2[d] = pd;
  }
}

// ------ gather layer 2 + log_softmax: 4-edge-parallel, UNIFORM trip count ---
__global__ __launch_bounds__(256) void gather2(
    const int* __restrict__ csr_src, const int* __restrict__ row_start,
    const float* __restrict__ a_src, const float* __restrict__ a_dst,
    const ushort_t* __restrict__ h2, const float* __restrict__ b,
    float* __restrict__ out, int n) {
  const int d = blockIdx.x * 4 + (threadIdx.x >> 6);
  const int lane = threadIdx.x & 63;
  if (d >= n) return;
  const int rs = row_start[d];
  const int deg = row_start[d + 1] - rs;
  const float adv = a_dst[d];

  const int sub = lane >> 4;
  const int q = lane & 15;
  float lsum = 0.f;
  f32x4 acc = {0.f, 0.f, 0.f, 0.f};
  for (int t0 = 0; t0 < deg; t0 += 64) {
    int myi = t0 + lane;
    int mys = 0;
    float myc = 0.f;
    if (myi < deg) {
      mys = csr_src[rs + myi];
      myc = __expf(lrelu(a_src[mys] + adv));
      lsum += myc;
    }
    const int nt = min(64, deg - t0);
    const int ntp = (nt + 3) & ~3;
    for (int e = sub; e < ntp; e += 4) {
      float cf = __shfl(myc, e, 64);
      int s = __shfl(mys, e, 64);
      ushort4 hv = *(const ushort4*)&h2[(size_t)s * F2 + q * 4];
      acc[0] += cf * bf2f(hv.x);
      acc[1] += cf * bf2f(hv.y);
      acc[2] += cf * bf2f(hv.z);
      acc[3] += cf * bf2f(hv.w);
    }
  }
  #pragma unroll
  for (int off = 32; off > 0; off >>= 1) lsum += __shfl_xor(lsum, off, 64);
  const float rden = 1.f / lsum;

  #pragma unroll
  for (int j = 0; j < 4; ++j) {
    acc[j] += __shfl_xor(acc[j], 16, 64);
    acc[j] += __shfl_xor(acc[j], 32, 64);
  }
  float vx = __shfl(acc[0], lane >> 2, 64);
  float vy = __shfl(acc[1], lane >> 2, 64);
  float vz = __shfl(acc[2], lane >> 2, 64);
  float vw = __shfl(acc[3], lane >> 2, 64);
  int c3 = lane & 3;
  float v = (c3 == 0) ? vx : (c3 == 1) ? vy : (c3 == 2) ? vz : vw;
  v = v * rden + b[lane];
  float m = v;
  #pragma unroll
  for (int off = 32; off > 0; off >>= 1) m = fmaxf(m, __shfl_xor(m, off, 64));
  float ex = __expf(v - m);
  float ss = ex;
  #pragma unroll
  for (int off = 32; off > 0; off >>= 1) ss += __shfl_xor(ss, off, 64);
  out[(size_t)d * F2 + lane] = v - m - __logf(ss);
}

// ------------------------------- launch -------------------------------------
extern "C" void kernel_launch(void* const* d_in, const int* in_sizes, int n_in,
                              void* d_out, int out_size, void* d_ws,
                              size_t ws_size, hipStream_t stream) {
  const float* x        = (const float*)d_in[0];
  const int*   ei       = (const int*)d_in[1];
  const float* W1       = (const float*)d_in[2];
  const float* att_src1 = (const float*)d_in[3];
  const float* att_dst1 = (const float*)d_in[4];
  const float* b1       = (const float*)d_in[5];
  const float* W2       = (const float*)d_in[6];
  const float* att_src2 = (const float*)d_in[7];
  const float* att_dst2 = (const float*)d_in[8];
  const float* b2       = (const float*)d_in[9];

  const int N = in_sizes[0] / 128;
  const int E0 = in_sizes[1] / 2;
  const int Etot = E0 + N;
  const int nb1024 = (N + 1023) / 1024;

  char* w = (char*)d_ws;
  size_t off = 0;
  auto alloc = [&](size_t bytes) {
    char* p = w + off;
    off += (bytes + 255) & ~(size_t)255;
    return p;
  };
  uchar_t*  h1        = (uchar_t*) alloc((size_t)N * F1 * 1);
  ushort_t* h1out     = (ushort_t*)alloc((size_t)N * F1 * 2);
  ushort_t* h2b       = (ushort_t*)alloc((size_t)N * F2 * 2);
  int*      csr_src   = (int*)     alloc((size_t)Etot * 4);
  int*      eslot     = (int*)     alloc((size_t)Etot * 4);
  int*      row_start = (int*)     alloc((size_t)(N + 1) * 4);
  int*      cc        = (int*)     alloc(((size_t)N + nb1024) * 4);
  int*      counts    = cc;
  int*      btot      = cc + N;
  float*    a_src1    = (float*)   alloc((size_t)N * HEADS1 * 4);
  float*    a_dst1    = (float*)   alloc((size_t)N * HEADS1 * 4);
  float*    a_src2    = (float*)   alloc((size_t)N * 4);
  float*    a_dst2    = (float*)   alloc((size_t)N * 4);
  ushort_t* W1ext     = (ushort_t*)alloc(320 * 128 * 2);
  ushort_t* W2t       = (ushort_t*)alloc(256 * 64 * 2);
  float*    w_s2      = (float*)   alloc(256 * 4);
  float*    w_d2      = (float*)   alloc(256 * 4);

  hipMemsetAsync(cc, 0, ((size_t)N + nb1024) * 4, stream);

  dim3 blk(256);
  const int eb = (Etot + 255) / 256;
  const int gy = (N + 63) / 64;
  const int GB1 = gy;   // row-stripe gemm1: one block per 64 rows

  kernelA<<<225 + eb, blk, 0, stream>>>(W1, W2, att_src1, att_dst1, att_src2,
                                        att_dst2, W1ext, W2t, w_s2, w_d2,
                                        ei, E0, Etot, counts, eslot);
  scan_fused<<<nb1024, blk, 0, stream>>>(counts, row_start, btot, N);

  kernelB<<<GB1 + eb, blk, 0, stream>>>(
      x, W1ext, h1, N, ei, E0, Etot, row_start, eslot, csr_src,
      a_src1, a_dst1, GB1);

  gather1<<<(N + 3) / 4, blk, 0, stream>>>(csr_src, row_start, a_src1, a_dst1,
                                           h1, b1, w_s2, w_d2, h1out, a_src2,
                                           a_dst2, N);

  gemm_bf16<<<dim3(F2 / 64, gy), blk, 0, stream>>>(h1out, W2t, h2b, N, F2, F1);
  gather2<<<(N + 3) / 4, blk, 0, stream>>>(csr_src, row_start, a_src2, a_dst2,
                                           h2b, b2, (float*)d_out, N);
}